// Round 1
// baseline (5804.465 us; speedup 1.0000x reference)
//
#include <hip/hip_runtime.h>
#include <hip/hip_fp16.h>

typedef _Float16 half8 __attribute__((ext_vector_type(8)));
typedef float floatx4 __attribute__((ext_vector_type(4)));

constexpr int kS = 4096;
constexpr int kD = 1024;
constexpr int kH = 16;
constexpr int kDh = 64;
constexpr int kF = 4096;

// ---------------------------------------------------------------- convert
__global__ __launch_bounds__(256) void convert_kernel(
    const float* __restrict__ src, _Float16* __restrict__ dst, int n) {
  int i = blockIdx.x * 256 + threadIdx.x;
  if (i < n) dst[i] = (_Float16)src[i];
}

// ---------------------------------------------------------------- LayerNorm (D=1024) -> fp16
__global__ __launch_bounds__(256) void ln_kernel(
    const float* __restrict__ x, const float* __restrict__ scale,
    const float* __restrict__ bias, _Float16* __restrict__ xn) {
  const int row = blockIdx.x;
  const int tid = threadIdx.x;
  const float* xr = x + (size_t)row * kD;
  float v[4];
  float s = 0.f, sq = 0.f;
#pragma unroll
  for (int i = 0; i < 4; ++i) {
    v[i] = xr[tid + 256 * i];
    s += v[i];
    sq += v[i] * v[i];
  }
  for (int off = 32; off; off >>= 1) {
    s += __shfl_xor(s, off);
    sq += __shfl_xor(sq, off);
  }
  __shared__ float red[8];
  const int wv = tid >> 6;
  if ((tid & 63) == 0) { red[wv] = s; red[wv + 4] = sq; }
  __syncthreads();
  s = red[0] + red[1] + red[2] + red[3];
  sq = red[4] + red[5] + red[6] + red[7];
  const float mean = s * (1.0f / kD);
  const float var = sq * (1.0f / kD) - mean * mean;
  const float rstd = rsqrtf(var + 1e-6f);
#pragma unroll
  for (int i = 0; i < 4; ++i) {
    int d = tid + 256 * i;
    xn[(size_t)row * kD + d] = (_Float16)((v[i] - mean) * rstd * scale[d] + bias[d]);
  }
}

// ---------------------------------------------------------------- per-head qk LayerNorm (Dh=64, no bias), in place on fp16
__global__ __launch_bounds__(256) void qknorm_kernel(
    _Float16* __restrict__ t, const float* __restrict__ scale) {
  const int row = (blockIdx.x << 2) + (threadIdx.x >> 6);
  const int lane = threadIdx.x & 63;
  _Float16* tr = t + (size_t)row * kDh;
  const float val = (float)tr[lane];
  float s = val;
  for (int off = 32; off; off >>= 1) s += __shfl_xor(s, off);
  const float mean = s * (1.0f / kDh);
  const float dv = val - mean;
  float sq = dv * dv;
  for (int off = 32; off; off >>= 1) sq += __shfl_xor(sq, off);
  const float rstd = rsqrtf(sq * (1.0f / kDh) + 1e-6f);
  tr[lane] = (_Float16)(dv * rstd * scale[lane]);
}

// ---------------------------------------------------------------- fp16 MFMA GEMM, 128x128 tile, BK=32
// C[m][n] = act(A[m][k] * B[k][n] + bias[n] (+ res)) ; A,B fp16 row-major.
#define LDSW 40  // 32 + 8 pad halves per row; keeps 16B alignment (80 B rows)

__global__ __launch_bounds__(256) void gemm_kernel(
    const _Float16* __restrict__ A, const _Float16* __restrict__ B,
    const float* __restrict__ bias, const float* __restrict__ res,
    float* __restrict__ outf, _Float16* __restrict__ outh,
    int N, int K, int apply_gelu) {
  __shared__ alignas(16) _Float16 As[128 * LDSW];
  __shared__ alignas(16) _Float16 Bs[128 * LDSW];

  const int tid = threadIdx.x;
  const int lane = tid & 63;
  const int wave = tid >> 6;
  const int wm = (wave >> 1) * 64;
  const int wn = (wave & 1) * 64;
  const int m0 = blockIdx.x * 128;
  const int n0 = blockIdx.y * 128;
  const int lrow = lane & 15;
  const int quad = lane >> 4;

  floatx4 acc[4][4] = {};

  for (int k0 = 0; k0 < K; k0 += 32) {
#pragma unroll
    for (int it = 0; it < 2; ++it) {
      const int c = it * 256 + tid;
      // A tile: 128 rows x 32 halves
      const int ar = c >> 2, ak = (c & 3) << 3;
      uint4 av = *reinterpret_cast<const uint4*>(A + (size_t)(m0 + ar) * K + k0 + ak);
      *reinterpret_cast<uint4*>(&As[ar * LDSW + ak]) = av;
      // B tile: 32 k-rows x 128 n, stored transposed [n][k]
      const int kr = c >> 4, nb = (c & 15) << 3;
      uint4 bv = *reinterpret_cast<const uint4*>(B + (size_t)(k0 + kr) * N + n0 + nb);
      const _Float16* bh = reinterpret_cast<const _Float16*>(&bv);
#pragma unroll
      for (int j = 0; j < 8; ++j) Bs[(nb + j) * LDSW + kr] = bh[j];
    }
    __syncthreads();

    half8 af[4], bf[4];
#pragma unroll
    for (int i = 0; i < 4; ++i) {
      af[i] = *reinterpret_cast<const half8*>(&As[(wm + i * 16 + lrow) * LDSW + quad * 8]);
      bf[i] = *reinterpret_cast<const half8*>(&Bs[(wn + i * 16 + lrow) * LDSW + quad * 8]);
    }
#pragma unroll
    for (int i = 0; i < 4; ++i)
#pragma unroll
      for (int j = 0; j < 4; ++j)
        acc[i][j] = __builtin_amdgcn_mfma_f32_16x16x32_f16(af[i], bf[j], acc[i][j], 0, 0, 0);
    __syncthreads();
  }

  // epilogue: C/D layout col=lane&15, row=(lane>>4)*4+r
#pragma unroll
  for (int i = 0; i < 4; ++i) {
    const int gm = m0 + wm + i * 16 + quad * 4;
#pragma unroll
    for (int j = 0; j < 4; ++j) {
      const int gn = n0 + wn + j * 16 + lrow;
      const float bn = bias[gn];
#pragma unroll
      for (int r = 0; r < 4; ++r) {
        float vv = acc[i][j][r] + bn;
        const size_t idx = (size_t)(gm + r) * N + gn;
        if (res) vv += res[idx];
        if (apply_gelu) {
          float xv = vv;
          vv = 0.5f * xv * (1.0f + tanhf(0.7978845608028654f * (xv + 0.044715f * xv * xv * xv)));
        }
        if (outh) outh[idx] = (_Float16)vv;
        else outf[idx] = vv;
      }
    }
  }
}

// ---------------------------------------------------------------- attention: one block per (query row, head), causal
__global__ __launch_bounds__(256) void attn_kernel(
    const _Float16* __restrict__ q, const _Float16* __restrict__ k,
    const _Float16* __restrict__ v, _Float16* __restrict__ o) {
  const int qi = blockIdx.x;
  const int h = blockIdx.y;
  const int tid = threadIdx.x;

  __shared__ float qs[kDh];
  __shared__ float ps[kS];
  __shared__ float wred[4];
  __shared__ float ored[4][kDh];

  if (tid < kDh) qs[tid] = (float)q[((size_t)qi * kH + h) * kDh + tid];
  __syncthreads();

  const int nk = qi + 1;                 // causal: keys 0..qi
  const int nit = (nk + 255) >> 8;

  // pass 1: scores into LDS, track max
  float mymax = -1e30f;
  for (int it = 0; it < nit; ++it) {
    const int j = tid + (it << 8);
    float sv = -1e30f;
    if (j < nk) {
      const half8* kr8 = reinterpret_cast<const half8*>(k + ((size_t)j * kH + h) * kDh);
      float d = 0.f;
#pragma unroll
      for (int c8 = 0; c8 < 8; ++c8) {
        half8 kv = kr8[c8];
#pragma unroll
        for (int e = 0; e < 8; ++e) d += qs[c8 * 8 + e] * (float)kv[e];
      }
      sv = d * 0.125f;  // 1/sqrt(64)
    }
    ps[j] = sv;
    mymax = fmaxf(mymax, sv);
  }
  for (int off = 32; off; off >>= 1) mymax = fmaxf(mymax, __shfl_xor(mymax, off));
  if ((tid & 63) == 0) wred[tid >> 6] = mymax;
  __syncthreads();
  const float gmax = fmaxf(fmaxf(wred[0], wred[1]), fmaxf(wred[2], wred[3]));
  __syncthreads();

  // pass 2: exp + sum
  float mysum = 0.f;
  for (int it = 0; it < nit; ++it) {
    const int j = tid + (it << 8);
    const float p = (j < nk) ? __expf(ps[j] - gmax) : 0.0f;
    ps[j] = p;
    mysum += p;
  }
  for (int off = 32; off; off >>= 1) mysum += __shfl_xor(mysum, off);
  if ((tid & 63) == 0) wred[tid >> 6] = mysum;
  __syncthreads();
  const float inv = 1.0f / (wred[0] + wred[1] + wred[2] + wred[3]);

  // pass 3: o = sum_j p_j * v_j ; wave w handles j = w mod 4, lane = dim
  const int d = tid & 63;
  const int wv = tid >> 6;
  float oacc = 0.f;
  for (int j = wv; j < nk; j += 4)
    oacc += ps[j] * (float)v[((size_t)j * kH + h) * kDh + d];
  ored[wv][d] = oacc;
  __syncthreads();
  if (tid < kDh) {
    const float r = (ored[0][tid] + ored[1][tid] + ored[2][tid] + ored[3][tid]) * inv;
    o[((size_t)qi * kH + h) * kDh + tid] = (_Float16)r;
  }
}

// ---------------------------------------------------------------- launch
extern "C" void kernel_launch(void* const* d_in, const int* in_sizes, int n_in,
                              void* d_out, int out_size, void* d_ws, size_t ws_size,
                              hipStream_t stream) {
  const float* x        = (const float*)d_in[0];
  // d_in[1] = mask: known causal, unused
  const float* ln_scale = (const float*)d_in[2];
  const float* ln_bias  = (const float*)d_in[3];
  const float* w_in     = (const float*)d_in[4];
  const float* b_in     = (const float*)d_in[5];
  const float* wq       = (const float*)d_in[6];
  const float* bq       = (const float*)d_in[7];
  const float* wk       = (const float*)d_in[8];
  const float* bk       = (const float*)d_in[9];
  const float* wv       = (const float*)d_in[10];
  const float* bv       = (const float*)d_in[11];
  const float* qn_scale = (const float*)d_in[12];
  const float* kn_scale = (const float*)d_in[13];
  const float* w_mo     = (const float*)d_in[14];
  const float* b_mo     = (const float*)d_in[15];
  const float* w_ao     = (const float*)d_in[16];
  const float* b_ao     = (const float*)d_in[17];
  float* out = (float*)d_out;

  char* ws = (char*)d_ws;
  size_t off = 0;
  auto alloc = [&](size_t bytes) { char* p = ws + off; off += bytes; return p; };
  _Float16* xn     = (_Float16*)alloc((size_t)kS * kD * 2);
  _Float16* w_in_h = (_Float16*)alloc((size_t)kD * kF * 2);
  _Float16* wq_h   = (_Float16*)alloc((size_t)kD * kD * 2);
  _Float16* wk_h   = (_Float16*)alloc((size_t)kD * kD * 2);
  _Float16* wv_h   = (_Float16*)alloc((size_t)kD * kD * 2);
  _Float16* w_mo_h = (_Float16*)alloc((size_t)kF * kD * 2);
  _Float16* w_ao_h = (_Float16*)alloc((size_t)kD * kD * 2);
  _Float16* h_h    = (_Float16*)alloc((size_t)kS * kF * 2);
  _Float16* q_h    = (_Float16*)alloc((size_t)kS * kD * 2);
  _Float16* k_h    = (_Float16*)alloc((size_t)kS * kD * 2);
  _Float16* v_h    = (_Float16*)alloc((size_t)kS * kD * 2);
  _Float16* o_h    = (_Float16*)alloc((size_t)kS * kD * 2);

  auto conv = [&](const float* s, _Float16* dst, int n) {
    convert_kernel<<<(n + 255) / 256, 256, 0, stream>>>(s, dst, n);
  };
  conv(w_in, w_in_h, kD * kF);
  conv(wq, wq_h, kD * kD);
  conv(wk, wk_h, kD * kD);
  conv(wv, wv_h, kD * kD);
  conv(w_mo, w_mo_h, kF * kD);
  conv(w_ao, w_ao_h, kD * kD);

  ln_kernel<<<kS, 256, 0, stream>>>(x, ln_scale, ln_bias, xn);

  // h = gelu(xn @ w_in + b_in)  [S,F] fp16
  gemm_kernel<<<dim3(kS / 128, kF / 128), 256, 0, stream>>>(
      xn, w_in_h, b_in, nullptr, nullptr, h_h, kF, kD, 1);
  // q,k,v = xn @ w{q,k,v} + b  [S,D] fp16
  gemm_kernel<<<dim3(kS / 128, kD / 128), 256, 0, stream>>>(
      xn, wq_h, bq, nullptr, nullptr, q_h, kD, kD, 0);
  gemm_kernel<<<dim3(kS / 128, kD / 128), 256, 0, stream>>>(
      xn, wk_h, bk, nullptr, nullptr, k_h, kD, kD, 0);
  gemm_kernel<<<dim3(kS / 128, kD / 128), 256, 0, stream>>>(
      xn, wv_h, bv, nullptr, nullptr, v_h, kD, kD, 0);

  qknorm_kernel<<<kS * kH / 4, 256, 0, stream>>>(q_h, qn_scale);
  qknorm_kernel<<<kS * kH / 4, 256, 0, stream>>>(k_h, kn_scale);

  attn_kernel<<<dim3(kS, kH), 256, 0, stream>>>(q_h, k_h, v_h, o_h);

  // out = x + (h @ w_mo + b_mo)
  gemm_kernel<<<dim3(kS / 128, kD / 128), 256, 0, stream>>>(
      h_h, w_mo_h, b_mo, x, out, nullptr, kD, kF, 0);
  // out += (o @ w_ao + b_ao)
  gemm_kernel<<<dim3(kS / 128, kD / 128), 256, 0, stream>>>(
      o_h, w_ao_h, b_ao, out, out, nullptr, kD, kD, 0);
}

// Round 3
// 1090.759 us; speedup vs baseline: 5.3215x; 5.3215x over previous
//
#include <hip/hip_runtime.h>
#include <hip/hip_fp16.h>

typedef _Float16 half8 __attribute__((ext_vector_type(8)));
typedef float floatx4 __attribute__((ext_vector_type(4)));

constexpr int kS = 4096;
constexpr int kD = 1024;
constexpr int kH = 16;
constexpr int kDh = 64;
constexpr int kF = 4096;

// ---------------------------------------------------------------- convert
__global__ __launch_bounds__(256) void convert_kernel(
    const float* __restrict__ src, _Float16* __restrict__ dst, int n) {
  int i = blockIdx.x * 256 + threadIdx.x;
  if (i < n) dst[i] = (_Float16)src[i];
}

// ---------------------------------------------------------------- LayerNorm (D=1024) -> fp16
__global__ __launch_bounds__(256) void ln_kernel(
    const float* __restrict__ x, const float* __restrict__ scale,
    const float* __restrict__ bias, _Float16* __restrict__ xn) {
  const int row = blockIdx.x;
  const int tid = threadIdx.x;
  const float* xr = x + (size_t)row * kD;
  float v[4];
  float s = 0.f, sq = 0.f;
#pragma unroll
  for (int i = 0; i < 4; ++i) {
    v[i] = xr[tid + 256 * i];
    s += v[i];
    sq += v[i] * v[i];
  }
  for (int off = 32; off; off >>= 1) {
    s += __shfl_xor(s, off);
    sq += __shfl_xor(sq, off);
  }
  __shared__ float red[8];
  const int wv = tid >> 6;
  if ((tid & 63) == 0) { red[wv] = s; red[wv + 4] = sq; }
  __syncthreads();
  s = red[0] + red[1] + red[2] + red[3];
  sq = red[4] + red[5] + red[6] + red[7];
  const float mean = s * (1.0f / kD);
  const float var = sq * (1.0f / kD) - mean * mean;
  const float rstd = rsqrtf(var + 1e-6f);
#pragma unroll
  for (int i = 0; i < 4; ++i) {
    int d = tid + 256 * i;
    xn[(size_t)row * kD + d] = (_Float16)((v[i] - mean) * rstd * scale[d] + bias[d]);
  }
}

// ---------------------------------------------------------------- per-head qk LayerNorm (Dh=64, no bias), in place on fp16
__global__ __launch_bounds__(256) void qknorm_kernel(
    _Float16* __restrict__ t, const float* __restrict__ scale) {
  const int row = (blockIdx.x << 2) + (threadIdx.x >> 6);
  const int lane = threadIdx.x & 63;
  _Float16* tr = t + (size_t)row * kDh;
  const float val = (float)tr[lane];
  float s = val;
  for (int off = 32; off; off >>= 1) s += __shfl_xor(s, off);
  const float mean = s * (1.0f / kDh);
  const float dv = val - mean;
  float sq = dv * dv;
  for (int off = 32; off; off >>= 1) sq += __shfl_xor(sq, off);
  const float rstd = rsqrtf(sq * (1.0f / kDh) + 1e-6f);
  tr[lane] = (_Float16)(dv * rstd * scale[lane]);
}

// ---------------------------------------------------------------- fp16 MFMA GEMM, 128x128 tile, BK=32
#define LDSW 40  // 32 + 8 pad halves per row; keeps 16B alignment (80 B rows)

__global__ __launch_bounds__(256) void gemm_kernel(
    const _Float16* __restrict__ A, const _Float16* __restrict__ B,
    const float* __restrict__ bias, const float* __restrict__ res,
    float* __restrict__ outf, _Float16* __restrict__ outh,
    int N, int K, int apply_gelu) {
  __shared__ alignas(16) _Float16 As[128 * LDSW];
  __shared__ alignas(16) _Float16 Bs[128 * LDSW];

  const int tid = threadIdx.x;
  const int lane = tid & 63;
  const int wave = tid >> 6;
  const int wm = (wave >> 1) * 64;
  const int wn = (wave & 1) * 64;
  const int m0 = blockIdx.x * 128;
  const int n0 = blockIdx.y * 128;
  const int lrow = lane & 15;
  const int quad = lane >> 4;

  floatx4 acc[4][4] = {};

  for (int k0 = 0; k0 < K; k0 += 32) {
#pragma unroll
    for (int it = 0; it < 2; ++it) {
      const int c = it * 256 + tid;
      const int ar = c >> 2, ak = (c & 3) << 3;   // 128 rows x 32 halves
      uint4 av = *reinterpret_cast<const uint4*>(A + (size_t)(m0 + ar) * K + k0 + ak);
      *reinterpret_cast<uint4*>(&As[ar * LDSW + ak]) = av;
      const int kr = c >> 4, nb = (c & 15) << 3;  // 32 k-rows x 128 n
      uint4 bv = *reinterpret_cast<const uint4*>(B + (size_t)(k0 + kr) * N + n0 + nb);
      const _Float16* bh = reinterpret_cast<const _Float16*>(&bv);
#pragma unroll
      for (int j = 0; j < 8; ++j) Bs[(nb + j) * LDSW + kr] = bh[j];
    }
    __syncthreads();

    half8 af[4], bf[4];
#pragma unroll
    for (int i = 0; i < 4; ++i) {
      af[i] = *reinterpret_cast<const half8*>(&As[(wm + i * 16 + lrow) * LDSW + quad * 8]);
      bf[i] = *reinterpret_cast<const half8*>(&Bs[(wn + i * 16 + lrow) * LDSW + quad * 8]);
    }
#pragma unroll
    for (int i = 0; i < 4; ++i)
#pragma unroll
      for (int j = 0; j < 4; ++j)
        acc[i][j] = __builtin_amdgcn_mfma_f32_16x16x32_f16(af[i], bf[j], acc[i][j], 0, 0, 0);
    __syncthreads();
  }

#pragma unroll
  for (int i = 0; i < 4; ++i) {
    const int gm = m0 + wm + i * 16 + quad * 4;
#pragma unroll
    for (int j = 0; j < 4; ++j) {
      const int gn = n0 + wn + j * 16 + lrow;
      const float bn = bias[gn];
#pragma unroll
      for (int r = 0; r < 4; ++r) {
        float vv = acc[i][j][r] + bn;
        const size_t idx = (size_t)(gm + r) * N + gn;
        if (res) vv += res[idx];
        if (apply_gelu) {
          float xv = vv;
          vv = 0.5f * xv * (1.0f + tanhf(0.7978845608028654f * (xv + 0.044715f * xv * xv * xv)));
        }
        if (outh) outh[idx] = (_Float16)vv;
        else outf[idx] = vv;
      }
    }
  }
}

// ---------------------------------------------------------------- flash attention (MFMA), causal
// One block (4 waves) per (128-row Q tile, head). K-tile = 64.
__global__ __launch_bounds__(256) void fattn_kernel(
    const _Float16* __restrict__ Q, const _Float16* __restrict__ K,
    const _Float16* __restrict__ V, _Float16* __restrict__ O) {
  constexpr int PAD = 72;  // 144 B rows: 16B-aligned, 2-way bank alias only
  __shared__ alignas(16) _Float16 Qs[128 * PAD];  // 18 KB
  __shared__ alignas(16) _Float16 Ks[64 * PAD];   // 9 KB
  __shared__ alignas(16) _Float16 Vt[64 * PAD];   // 9 KB (transposed: [d][key])
  __shared__ alignas(16) _Float16 Ps[128 * PAD];  // 18 KB (rows = wave*32 + local)

  const int tid = threadIdx.x;
  const int lane = tid & 63;
  const int wave = tid >> 6;
  const int lrow = lane & 15;
  const int quad = lane >> 4;
  const int h = blockIdx.y;
  const int q0 = blockIdx.x * 128;

  // stage Q tile (128 x 64 halves = 1024 half8 chunks), folding scale 1/8
#pragma unroll
  for (int it = 0; it < 4; ++it) {
    const int c = it * 256 + tid;
    const int r = c >> 3, dd = (c & 7) << 3;
    half8 qv = *reinterpret_cast<const half8*>(Q + ((size_t)(q0 + r) * kH + h) * kDh + dd);
#pragma unroll
    for (int j = 0; j < 8; ++j) qv[j] = (_Float16)((float)qv[j] * 0.125f);
    *reinterpret_cast<half8*>(&Qs[r * PAD + dd]) = qv;
  }
  __syncthreads();

  half8 qf[2][2];
#pragma unroll
  for (int i = 0; i < 2; ++i)
#pragma unroll
    for (int kt = 0; kt < 2; ++kt)
      qf[i][kt] = *reinterpret_cast<const half8*>(
          &Qs[(wave * 32 + i * 16 + lrow) * PAD + kt * 32 + quad * 8]);

  float mstate[2][4], lstate[2][4];
  floatx4 oacc[2][4] = {};
#pragma unroll
  for (int i = 0; i < 2; ++i)
#pragma unroll
    for (int r = 0; r < 4; ++r) { mstate[i][r] = -1e30f; lstate[i][r] = 0.f; }

  const int qw = q0 + wave * 32;   // first q row owned by this wave
  const int ntiles = (q0 + 128) / 64;

  for (int t = 0; t < ntiles; ++t) {
    const int k0 = t * 64;
    __syncthreads();  // previous iteration's K/Vt frag reads complete
    {  // stage K (64x64) and V^T: 512 half8 chunks over 2 iterations
#pragma unroll
      for (int it = 0; it < 2; ++it) {
        const int c = it * 256 + tid;
        const int r = c >> 3, dd = (c & 7) << 3;
        const size_t g = ((size_t)(k0 + r) * kH + h) * kDh + dd;
        *reinterpret_cast<half8*>(&Ks[r * PAD + dd]) =
            *reinterpret_cast<const half8*>(K + g);
        half8 vv = *reinterpret_cast<const half8*>(V + g);
#pragma unroll
        for (int j = 0; j < 8; ++j) Vt[(dd + j) * PAD + r] = vv[j];
      }
    }
    __syncthreads();

    if (k0 > qw + 31) continue;  // whole wave-tile above diagonal

    // S = Q K^T : rows q = qw + i*16 + quad*4 + r, cols k0 + jt*16 + lrow
    floatx4 sacc[2][4] = {};
#pragma unroll
    for (int kt = 0; kt < 2; ++kt)
#pragma unroll
      for (int jt = 0; jt < 4; ++jt) {
        half8 bf = *reinterpret_cast<const half8*>(
            &Ks[(jt * 16 + lrow) * PAD + kt * 32 + quad * 8]);
        sacc[0][jt] = __builtin_amdgcn_mfma_f32_16x16x32_f16(qf[0][kt], bf, sacc[0][jt], 0, 0, 0);
        sacc[1][jt] = __builtin_amdgcn_mfma_f32_16x16x32_f16(qf[1][kt], bf, sacc[1][jt], 0, 0, 0);
      }

    if (k0 + 63 > qw) {  // diagonal tile: causal mask
#pragma unroll
      for (int i = 0; i < 2; ++i)
#pragma unroll
        for (int jt = 0; jt < 4; ++jt) {
          const int kg = k0 + jt * 16 + lrow;
#pragma unroll
          for (int r = 0; r < 4; ++r)
            if (kg > qw + i * 16 + quad * 4 + r) sacc[i][jt][r] = -1e30f;
        }
    }

    // online softmax per row (16-lane group shares a row)
#pragma unroll
    for (int i = 0; i < 2; ++i)
#pragma unroll
      for (int r = 0; r < 4; ++r) {
        float mx = fmaxf(fmaxf(sacc[i][0][r], sacc[i][1][r]),
                         fmaxf(sacc[i][2][r], sacc[i][3][r]));
#pragma unroll
        for (int off = 8; off; off >>= 1) mx = fmaxf(mx, __shfl_xor(mx, off));
        const float mnew = fmaxf(mstate[i][r], mx);
        const float alpha = __expf(mstate[i][r] - mnew);
        mstate[i][r] = mnew;
        float rs = 0.f;
#pragma unroll
        for (int jt = 0; jt < 4; ++jt) {
          const float p = __expf(sacc[i][jt][r] - mnew);
          sacc[i][jt][r] = p;
          rs += p;
        }
#pragma unroll
        for (int off = 8; off; off >>= 1) rs += __shfl_xor(rs, off);
        lstate[i][r] = lstate[i][r] * alpha + rs;
#pragma unroll
        for (int jt = 0; jt < 4; ++jt) oacc[i][jt][r] *= alpha;
      }

    // P: C-layout regs -> LDS fp16 (wave-private region; DS ops in-order per wave)
#pragma unroll
    for (int i = 0; i < 2; ++i)
#pragma unroll
      for (int jt = 0; jt < 4; ++jt)
#pragma unroll
        for (int r = 0; r < 4; ++r)
          Ps[(wave * 32 + i * 16 + quad * 4 + r) * PAD + jt * 16 + lrow] =
              (_Float16)sacc[i][jt][r];

    // O += P V : A-frags from Ps, B-frags from Vt
#pragma unroll
    for (int kt = 0; kt < 2; ++kt) {
      half8 pf0 = *reinterpret_cast<const half8*>(
          &Ps[(wave * 32 + 0 * 16 + lrow) * PAD + kt * 32 + quad * 8]);
      half8 pf1 = *reinterpret_cast<const half8*>(
          &Ps[(wave * 32 + 1 * 16 + lrow) * PAD + kt * 32 + quad * 8]);
#pragma unroll
      for (int jt = 0; jt < 4; ++jt) {
        half8 vf = *reinterpret_cast<const half8*>(
            &Vt[(jt * 16 + lrow) * PAD + kt * 32 + quad * 8]);
        oacc[0][jt] = __builtin_amdgcn_mfma_f32_16x16x32_f16(pf0, vf, oacc[0][jt], 0, 0, 0);
        oacc[1][jt] = __builtin_amdgcn_mfma_f32_16x16x32_f16(pf1, vf, oacc[1][jt], 0, 0, 0);
      }
    }
  }

  // epilogue: O /= l, store fp16 [S,H,Dh]
#pragma unroll
  for (int i = 0; i < 2; ++i) {
    const int qg = qw + i * 16 + quad * 4;
#pragma unroll
    for (int jt = 0; jt < 4; ++jt) {
      const int d = jt * 16 + lrow;
#pragma unroll
      for (int r = 0; r < 4; ++r)
        O[((size_t)(qg + r) * kH + h) * kDh + d] =
            (_Float16)(oacc[i][jt][r] / lstate[i][r]);
    }
  }
}

// ---------------------------------------------------------------- launch
extern "C" void kernel_launch(void* const* d_in, const int* in_sizes, int n_in,
                              void* d_out, int out_size, void* d_ws, size_t ws_size,
                              hipStream_t stream) {
  const float* x        = (const float*)d_in[0];
  // d_in[1] = mask: known causal, unused
  const float* ln_scale = (const float*)d_in[2];
  const float* ln_bias  = (const float*)d_in[3];
  const float* w_in     = (const float*)d_in[4];
  const float* b_in     = (const float*)d_in[5];
  const float* wq       = (const float*)d_in[6];
  const float* bq       = (const float*)d_in[7];
  const float* wk       = (const float*)d_in[8];
  const float* bk       = (const float*)d_in[9];
  const float* wv       = (const float*)d_in[10];
  const float* bv       = (const float*)d_in[11];
  const float* qn_scale = (const float*)d_in[12];
  const float* kn_scale = (const float*)d_in[13];
  const float* w_mo     = (const float*)d_in[14];
  const float* b_mo     = (const float*)d_in[15];
  const float* w_ao     = (const float*)d_in[16];
  const float* b_ao     = (const float*)d_in[17];
  float* out = (float*)d_out;

  char* ws = (char*)d_ws;
  size_t off = 0;
  auto alloc = [&](size_t bytes) { char* p = ws + off; off += bytes; return p; };
  _Float16* xn     = (_Float16*)alloc((size_t)kS * kD * 2);
  _Float16* w_in_h = (_Float16*)alloc((size_t)kD * kF * 2);
  _Float16* wq_h   = (_Float16*)alloc((size_t)kD * kD * 2);
  _Float16* wk_h   = (_Float16*)alloc((size_t)kD * kD * 2);
  _Float16* wv_h   = (_Float16*)alloc((size_t)kD * kD * 2);
  _Float16* w_mo_h = (_Float16*)alloc((size_t)kF * kD * 2);
  _Float16* w_ao_h = (_Float16*)alloc((size_t)kD * kD * 2);
  _Float16* h_h    = (_Float16*)alloc((size_t)kS * kF * 2);
  _Float16* q_h    = (_Float16*)alloc((size_t)kS * kD * 2);
  _Float16* k_h    = (_Float16*)alloc((size_t)kS * kD * 2);
  _Float16* v_h    = (_Float16*)alloc((size_t)kS * kD * 2);
  _Float16* o_h    = (_Float16*)alloc((size_t)kS * kD * 2);

  auto conv = [&](const float* s, _Float16* dst, int n) {
    convert_kernel<<<(n + 255) / 256, 256, 0, stream>>>(s, dst, n);
  };
  conv(w_in, w_in_h, kD * kF);
  conv(wq, wq_h, kD * kD);
  conv(wk, wk_h, kD * kD);
  conv(wv, wv_h, kD * kD);
  conv(w_mo, w_mo_h, kF * kD);
  conv(w_ao, w_ao_h, kD * kD);

  ln_kernel<<<kS, 256, 0, stream>>>(x, ln_scale, ln_bias, xn);

  gemm_kernel<<<dim3(kS / 128, kF / 128), 256, 0, stream>>>(
      xn, w_in_h, b_in, nullptr, nullptr, h_h, kF, kD, 1);
  gemm_kernel<<<dim3(kS / 128, kD / 128), 256, 0, stream>>>(
      xn, wq_h, bq, nullptr, nullptr, q_h, kD, kD, 0);
  gemm_kernel<<<dim3(kS / 128, kD / 128), 256, 0, stream>>>(
      xn, wk_h, bk, nullptr, nullptr, k_h, kD, kD, 0);
  gemm_kernel<<<dim3(kS / 128, kD / 128), 256, 0, stream>>>(
      xn, wv_h, bv, nullptr, nullptr, v_h, kD, kD, 0);

  qknorm_kernel<<<kS * kH / 4, 256, 0, stream>>>(q_h, qn_scale);
  qknorm_kernel<<<kS * kH / 4, 256, 0, stream>>>(k_h, kn_scale);

  fattn_kernel<<<dim3(kS / 128, kH), 256, 0, stream>>>(q_h, k_h, v_h, o_h);

  gemm_kernel<<<dim3(kS / 128, kD / 128), 256, 0, stream>>>(
      h_h, w_mo_h, b_mo, x, out, nullptr, kD, kF, 0);
  gemm_kernel<<<dim3(kS / 128, kD / 128), 256, 0, stream>>>(
      o_h, w_ao_h, b_ao, out, out, nullptr, kD, kD, 0);
}

// Round 4
// 523.623 us; speedup vs baseline: 11.0852x; 2.0831x over previous
//
#include <hip/hip_runtime.h>
#include <hip/hip_fp16.h>

typedef _Float16 half8 __attribute__((ext_vector_type(8)));
typedef float floatx4 __attribute__((ext_vector_type(4)));

constexpr int kS = 4096;
constexpr int kD = 1024;
constexpr int kH = 16;
constexpr int kDh = 64;
constexpr int kF = 4096;
constexpr int kNQKV = kF + 3 * kD;   // 7168
constexpr int kKOut = kF + kD;       // 5120

// async global->LDS, 16 B per lane; LDS dst must be wave-uniform base (lane*16 auto)
__device__ __forceinline__ void async_ld16(const void* g, void* l) {
  __builtin_amdgcn_global_load_lds(
      (const __attribute__((address_space(1))) void*)g,
      (__attribute__((address_space(3))) void*)l, 16, 0, 0);
}

// ---------------------------------------------------------------- weight transpose + fp32->fp16
// src [K][N] fp32 row-major; dst[(noff+n)*dldk + koff + k] = (fp16)src[k][n]
__global__ __launch_bounds__(256) void wtrans_kernel(
    const float* __restrict__ src, _Float16* __restrict__ dst,
    int N, int dldk, int noff, int koff) {
  __shared__ float t[32][33];
  const int tid = threadIdx.x;
  const int n0 = blockIdx.x * 32, k0 = blockIdx.y * 32;
#pragma unroll
  for (int i = 0; i < 4; ++i) {
    const int kl = (tid >> 5) + i * 8, nl = tid & 31;
    t[kl][nl] = src[(size_t)(k0 + kl) * N + n0 + nl];
  }
  __syncthreads();
#pragma unroll
  for (int i = 0; i < 4; ++i) {
    const int nl = (tid >> 5) + i * 8, kl = tid & 31;
    dst[(size_t)(noff + n0 + nl) * dldk + koff + k0 + kl] = (_Float16)t[kl][nl];
  }
}

// fp16 transpose: src [R][C] -> dst [C][R]
__global__ __launch_bounds__(256) void htrans_kernel(
    const _Float16* __restrict__ src, _Float16* __restrict__ dst, int R, int C) {
  __shared__ _Float16 t[32][34];
  const int tid = threadIdx.x;
  const int c0 = blockIdx.x * 32, r0 = blockIdx.y * 32;
#pragma unroll
  for (int i = 0; i < 4; ++i) {
    const int rl = (tid >> 5) + i * 8, cl = tid & 31;
    t[rl][cl] = src[(size_t)(r0 + rl) * C + c0 + cl];
  }
  __syncthreads();
#pragma unroll
  for (int i = 0; i < 4; ++i) {
    const int cl = (tid >> 5) + i * 8, rl = tid & 31;
    dst[(size_t)(c0 + cl) * R + r0 + rl] = t[rl][cl];
  }
}

// ---------------------------------------------------------------- bias prep
__global__ __launch_bounds__(256) void biasprep_kernel(
    const float* b_in, const float* bq, const float* bk, const float* bv,
    const float* b_mo, const float* b_ao, float* bcat, float* bsum) {
  const int i = blockIdx.x * 256 + threadIdx.x;
  if (i < kF) bcat[i] = b_in[i];
  else if (i < kF + kD) bcat[i] = bq[i - kF];
  else if (i < kF + 2 * kD) bcat[i] = bk[i - kF - kD];
  else if (i < kNQKV) bcat[i] = bv[i - kF - 2 * kD];
  else if (i < kNQKV + kD) bsum[i - kNQKV] = b_mo[i - kNQKV] + b_ao[i - kNQKV];
}

// ---------------------------------------------------------------- LayerNorm (D=1024) -> fp16
__global__ __launch_bounds__(256) void ln_kernel(
    const float* __restrict__ x, const float* __restrict__ scale,
    const float* __restrict__ bias, _Float16* __restrict__ xn) {
  const int row = blockIdx.x;
  const int tid = threadIdx.x;
  const float* xr = x + (size_t)row * kD;
  float v[4];
  float s = 0.f, sq = 0.f;
#pragma unroll
  for (int i = 0; i < 4; ++i) {
    v[i] = xr[tid + 256 * i];
    s += v[i];
    sq += v[i] * v[i];
  }
  for (int off = 32; off; off >>= 1) {
    s += __shfl_xor(s, off);
    sq += __shfl_xor(sq, off);
  }
  __shared__ float red[8];
  const int wv = tid >> 6;
  if ((tid & 63) == 0) { red[wv] = s; red[wv + 4] = sq; }
  __syncthreads();
  s = red[0] + red[1] + red[2] + red[3];
  sq = red[4] + red[5] + red[6] + red[7];
  const float mean = s * (1.0f / kD);
  const float var = sq * (1.0f / kD) - mean * mean;
  const float rstd = rsqrtf(var + 1e-6f);
#pragma unroll
  for (int i = 0; i < 4; ++i) {
    int d = tid + 256 * i;
    xn[(size_t)row * kD + d] = (_Float16)((v[i] - mean) * rstd * scale[d] + bias[d]);
  }
}

// ---------------------------------------------------------------- per-head qk LayerNorm
__global__ __launch_bounds__(256) void qknorm_kernel(
    _Float16* __restrict__ t, const float* __restrict__ scale, float smul) {
  const int row = (blockIdx.x << 2) + (threadIdx.x >> 6);
  const int lane = threadIdx.x & 63;
  _Float16* tr = t + (size_t)row * kDh;
  const float val = (float)tr[lane];
  float s = val;
  for (int off = 32; off; off >>= 1) s += __shfl_xor(s, off);
  const float mean = s * (1.0f / kDh);
  const float dv = val - mean;
  float sq = dv * dv;
  for (int off = 32; off; off >>= 1) sq += __shfl_xor(sq, off);
  const float rstd = rsqrtf(sq * (1.0f / kDh) + 1e-6f);
  tr[lane] = (_Float16)(dv * rstd * scale[lane] * smul);
}

// ---------------------------------------------------------------- fused QKV+MLP-in GEMM
// A = xn [4096][1024] fp16; B' = Wqkvin [7168][1024] fp16 (rows = out col).
// n<4096: gelu -> ho[m*5120+n]; else -> q/k/v [m*1024 + (n-4096)&1023].
__global__ __launch_bounds__(256) void gemm_qkvin(
    const _Float16* __restrict__ A, const _Float16* __restrict__ Bp,
    const float* __restrict__ bcat, _Float16* __restrict__ ho,
    _Float16* __restrict__ q, _Float16* __restrict__ k, _Float16* __restrict__ v) {
  __shared__ alignas(16) _Float16 Ts[16 * 512];  // 8 A chunks + 8 B chunks, 16 KB
  _Float16* As = Ts;
  _Float16* Bs = Ts + 8 * 512;

  const int tid = threadIdx.x;
  const int lane = tid & 63;
  const int wave = tid >> 6;
  const int wm = (wave >> 1) * 64;
  const int wn = (wave & 1) * 64;
  const int m0 = blockIdx.x * 128;
  const int n0 = blockIdx.y * 128;
  const int lrow = lane & 15;
  const int quad = lane >> 4;

  floatx4 acc[4][4] = {};

  for (int k0 = 0; k0 < kD; k0 += 32) {
    __syncthreads();
#pragma unroll
    for (int i = 0; i < 4; ++i) {
      const int chunk = wave * 4 + i;
      const int r = ((chunk & 7) << 4) + (lane >> 2);          // local row 0..127
      const int csrc = ((lane & 3) ^ ((r >> 1) & 3)) << 3;     // swizzled k-chunk
      const _Float16* src = (chunk < 8)
          ? A + (size_t)(m0 + r) * kD + k0 + csrc
          : Bp + (size_t)(n0 + r) * kD + k0 + csrc;
      async_ld16(src, Ts + chunk * 512);
    }
    __syncthreads();

    half8 af[4], bf[4];
#pragma unroll
    for (int i = 0; i < 4; ++i) {
      const int ra = wm + i * 16 + lrow;
      const int rb = wn + i * 16 + lrow;
      af[i] = *reinterpret_cast<const half8*>(&As[ra * 32 + ((quad ^ ((ra >> 1) & 3)) << 3)]);
      bf[i] = *reinterpret_cast<const half8*>(&Bs[rb * 32 + ((quad ^ ((rb >> 1) & 3)) << 3)]);
    }
#pragma unroll
    for (int i = 0; i < 4; ++i)
#pragma unroll
      for (int j = 0; j < 4; ++j)
        acc[i][j] = __builtin_amdgcn_mfma_f32_16x16x32_f16(af[i], bf[j], acc[i][j], 0, 0, 0);
  }

#pragma unroll
  for (int i = 0; i < 4; ++i) {
    const int gm = m0 + wm + i * 16 + quad * 4;
#pragma unroll
    for (int j = 0; j < 4; ++j) {
      const int gn = n0 + wn + j * 16 + lrow;
      const float bn = bcat[gn];
#pragma unroll
      for (int r = 0; r < 4; ++r) {
        float vv = acc[i][j][r] + bn;
        if (gn < kF) {
          const float xv = vv;
          vv = 0.5f * xv * (1.0f + tanhf(0.7978845608028654f * (xv + 0.044715f * xv * xv * xv)));
          ho[(size_t)(gm + r) * kKOut + gn] = (_Float16)vv;
        } else {
          const int reg = gn - kF;
          _Float16* dst = (reg < kD) ? q : (reg < 2 * kD) ? k : v;
          dst[(size_t)(gm + r) * kD + (reg & (kD - 1))] = (_Float16)vv;
        }
      }
    }
  }
}

// ---------------------------------------------------------------- fused out GEMM
// A = ho [4096][5120] fp16; B' = Wout [1024][5120] fp16.
// out[m][n] = x + A·B'^T + bsum. Tile 128x64, 4 waves (32 rows each).
__global__ __launch_bounds__(256) void gemm_out(
    const _Float16* __restrict__ A, const _Float16* __restrict__ Bp,
    const float* __restrict__ bsum, const float* __restrict__ x,
    float* __restrict__ out) {
  __shared__ alignas(16) _Float16 Ts[12 * 512];  // 8 A chunks + 4 B chunks, 12 KB
  _Float16* As = Ts;
  _Float16* Bs = Ts + 8 * 512;

  const int tid = threadIdx.x;
  const int lane = tid & 63;
  const int wave = tid >> 6;
  const int m0 = blockIdx.x * 128;
  const int n0 = blockIdx.y * 64;
  const int lrow = lane & 15;
  const int quad = lane >> 4;

  floatx4 acc[2][4] = {};

  for (int k0 = 0; k0 < kKOut; k0 += 32) {
    __syncthreads();
#pragma unroll
    for (int i = 0; i < 3; ++i) {
      const int chunk = wave * 3 + i;
      const int rl = (lane >> 2);
      const int csrc = ((lane & 3) ^ (((chunk < 8 ? ((chunk & 7) << 4) + rl
                                                 : ((chunk - 8) << 4) + rl) >> 1) & 3)) << 3;
      const _Float16* src;
      if (chunk < 8) {
        const int r = ((chunk & 7) << 4) + rl;
        src = A + (size_t)(m0 + r) * kKOut + k0 + csrc;
      } else {
        const int r = ((chunk - 8) << 4) + rl;
        src = Bp + (size_t)(n0 + r) * kKOut + k0 + csrc;
      }
      async_ld16(src, Ts + chunk * 512);
    }
    __syncthreads();

    half8 af[2], bf[4];
#pragma unroll
    for (int i = 0; i < 2; ++i) {
      const int ra = wave * 32 + i * 16 + lrow;
      af[i] = *reinterpret_cast<const half8*>(&As[ra * 32 + ((quad ^ ((ra >> 1) & 3)) << 3)]);
    }
#pragma unroll
    for (int j = 0; j < 4; ++j) {
      const int rb = j * 16 + lrow;
      bf[j] = *reinterpret_cast<const half8*>(&Bs[rb * 32 + ((quad ^ ((rb >> 1) & 3)) << 3)]);
    }
#pragma unroll
    for (int i = 0; i < 2; ++i)
#pragma unroll
      for (int j = 0; j < 4; ++j)
        acc[i][j] = __builtin_amdgcn_mfma_f32_16x16x32_f16(af[i], bf[j], acc[i][j], 0, 0, 0);
  }

#pragma unroll
  for (int i = 0; i < 2; ++i) {
    const int gm = m0 + wave * 32 + i * 16 + quad * 4;
#pragma unroll
    for (int j = 0; j < 4; ++j) {
      const int gn = n0 + j * 16 + lrow;
      const float bn = bsum[gn];
#pragma unroll
      for (int r = 0; r < 4; ++r) {
        const size_t idx = (size_t)(gm + r) * kD + gn;
        out[idx] = x[idx] + bn + acc[i][j][r];
      }
    }
  }
}

// ---------------------------------------------------------------- flash attention (MFMA), causal, balanced pairs
// grid (32, 16): block handles q-tiles {p, 63-p} (64 rows each) for head h. 65 k-tiles each.
__global__ __launch_bounds__(256) void fattn_kernel(
    const _Float16* __restrict__ Q, const _Float16* __restrict__ K,
    const _Float16* __restrict__ Vt, _Float16* __restrict__ ho) {
  __shared__ alignas(16) _Float16 Qs[64 * 64];   // 8 KB, swizzled rows (c ^ (r&7))
  __shared__ alignas(16) _Float16 Ks[64 * 64];   // 8 KB  rows=key
  __shared__ alignas(16) _Float16 Vs[64 * 64];   // 8 KB  rows=dh
  __shared__ alignas(16) _Float16 Ps[64 * 72];   // 9 KB  padded stride 72

  const int tid = threadIdx.x;
  const int lane = tid & 63;
  const int wave = tid >> 6;
  const int lrow = lane & 15;
  const int quad = lane >> 4;
  const int h = blockIdx.y;
  const int pair = blockIdx.x;

  const int rs = lane >> 3;        // staging: local row-in-chunk
  const int cs = lane & 7;         // staging: lds chunk col

  for (int pass = 0; pass < 2; ++pass) {
    const int qtile = pass ? (63 - pair) : pair;
    const int qbase = qtile * 64;

    __syncthreads();  // prior pass done with Qs
    {  // stage Q: 8 chunks of 8 rows; source col swizzled so LDS(r,c)=Q[r][c^(r&7)]
#pragma unroll
      for (int i = 0; i < 2; ++i) {
        const int chunk = wave * 2 + i;
        const int r = chunk * 8 + rs;
        async_ld16(Q + (size_t)(qbase + r) * kD + h * kDh + ((cs ^ (r & 7)) << 3),
                   Qs + chunk * 512);
      }
    }
    __syncthreads();

    half8 qf[2];
#pragma unroll
    for (int kt = 0; kt < 2; ++kt)
      qf[kt] = *reinterpret_cast<const half8*>(
          &Qs[(wave * 16 + lrow) * 64 + (((kt * 4 + quad) ^ (lrow & 7)) << 3)]);

    float mst[4], lst[4];
    floatx4 oacc[4] = {};
#pragma unroll
    for (int r = 0; r < 4; ++r) { mst[r] = -1e30f; lst[r] = 0.f; }

    const int qw = qbase + wave * 16;

    for (int t = 0; t <= qtile; ++t) {
      const int k0 = t * 64;
      __syncthreads();  // prior iter frag reads complete
      {  // stage K rows=key and V^T rows=dh (16 chunks / 4 waves)
#pragma unroll
        for (int i = 0; i < 4; ++i) {
          const int id = wave * 4 + i;
          if (id < 8) {
            const int r = id * 8 + rs;
            async_ld16(K + (size_t)(k0 + r) * kD + h * kDh + ((cs ^ (r & 7)) << 3),
                       Ks + id * 512);
          } else {
            const int c = id - 8;
            const int r = c * 8 + rs;  // dh
            async_ld16(Vt + (size_t)(h * kDh + r) * kS + k0 + ((cs ^ (r & 7)) << 3),
                       Vs + c * 512);
          }
        }
      }
      __syncthreads();

      const bool diag = (t == qtile);

      // S = Q K^T : S row = qw + quad*4 + r, col = k0 + jt*16 + lrow
      floatx4 sacc[4] = {};
#pragma unroll
      for (int jt = 0; jt < 4; ++jt) {
        if (diag && jt > wave) continue;  // fully masked
#pragma unroll
        for (int kt = 0; kt < 2; ++kt) {
          const int rb = jt * 16 + lrow;
          half8 bfk = *reinterpret_cast<const half8*>(
              &Ks[rb * 64 + (((kt * 4 + quad) ^ (lrow & 7)) << 3)]);
          sacc[jt] = __builtin_amdgcn_mfma_f32_16x16x32_f16(qf[kt], bfk, sacc[jt], 0, 0, 0);
        }
      }

      if (diag) {  // causal mask
#pragma unroll
        for (int jt = 0; jt < 4; ++jt) {
          const int kg = k0 + jt * 16 + lrow;
#pragma unroll
          for (int r = 0; r < 4; ++r)
            if (kg > qw + quad * 4 + r) sacc[jt][r] = -1e30f;
        }
      }

      // online softmax per row
#pragma unroll
      for (int r = 0; r < 4; ++r) {
        float mx = fmaxf(fmaxf(sacc[0][r], sacc[1][r]), fmaxf(sacc[2][r], sacc[3][r]));
#pragma unroll
        for (int off = 8; off; off >>= 1) mx = fmaxf(mx, __shfl_xor(mx, off));
        const float mnew = fmaxf(mst[r], mx);
        const float alpha = __expf(mst[r] - mnew);
        mst[r] = mnew;
        float rsum = 0.f;
#pragma unroll
        for (int jt = 0; jt < 4; ++jt) {
          const float p = __expf(sacc[jt][r] - mnew);
          sacc[jt][r] = p;
          rsum += p;
        }
#pragma unroll
        for (int off = 8; off; off >>= 1) rsum += __shfl_xor(rsum, off);
        lst[r] = lst[r] * alpha + rsum;
#pragma unroll
        for (int jt = 0; jt < 4; ++jt) oacc[jt][r] *= alpha;
      }

      // P: C-layout -> LDS (wave-private rows; stride 72 => ~2-way, free)
#pragma unroll
      for (int jt = 0; jt < 4; ++jt)
#pragma unroll
        for (int r = 0; r < 4; ++r)
          Ps[(wave * 16 + quad * 4 + r) * 72 + jt * 16 + lrow] = (_Float16)sacc[jt][r];

      // O += P V
      const int ktmax = (diag && wave < 2) ? 1 : 2;  // P zero for keys>=32 when wave<2 on diag
      for (int kt = 0; kt < ktmax; ++kt) {
        half8 pf = *reinterpret_cast<const half8*>(
            &Ps[(wave * 16 + lrow) * 72 + (kt * 4 + quad) * 8]);
#pragma unroll
        for (int jt = 0; jt < 4; ++jt) {
          const int rb = jt * 16 + lrow;  // dh row
          half8 vf = *reinterpret_cast<const half8*>(
              &Vs[rb * 64 + (((kt * 4 + quad) ^ (lrow & 7)) << 3)]);
          oacc[jt] = __builtin_amdgcn_mfma_f32_16x16x32_f16(pf, vf, oacc[jt], 0, 0, 0);
        }
      }
    }

    // epilogue: O /= l -> ho[:, 4096 + h*64 + dh]
#pragma unroll
    for (int jt = 0; jt < 4; ++jt) {
      const int d = jt * 16 + lrow;
#pragma unroll
      for (int r = 0; r < 4; ++r)
        ho[(size_t)(qw + quad * 4 + r) * kKOut + kF + h * kDh + d] =
            (_Float16)(oacc[jt][r] / lst[r]);
    }
  }
}

// ---------------------------------------------------------------- launch
extern "C" void kernel_launch(void* const* d_in, const int* in_sizes, int n_in,
                              void* d_out, int out_size, void* d_ws, size_t ws_size,
                              hipStream_t stream) {
  const float* x        = (const float*)d_in[0];
  // d_in[1] = mask: known causal, unused
  const float* ln_scale = (const float*)d_in[2];
  const float* ln_bias  = (const float*)d_in[3];
  const float* w_in     = (const float*)d_in[4];
  const float* b_in     = (const float*)d_in[5];
  const float* wq       = (const float*)d_in[6];
  const float* bq       = (const float*)d_in[7];
  const float* wk       = (const float*)d_in[8];
  const float* bk       = (const float*)d_in[9];
  const float* wv       = (const float*)d_in[10];
  const float* bv       = (const float*)d_in[11];
  const float* qn_scale = (const float*)d_in[12];
  const float* kn_scale = (const float*)d_in[13];
  const float* w_mo     = (const float*)d_in[14];
  const float* b_mo     = (const float*)d_in[15];
  const float* w_ao     = (const float*)d_in[16];
  const float* b_ao     = (const float*)d_in[17];
  float* out = (float*)d_out;

  char* ws = (char*)d_ws;
  size_t off = 0;
  auto alloc = [&](size_t bytes) { char* p = ws + off; off += bytes; return p; };
  _Float16* xn    = (_Float16*)alloc((size_t)kS * kD * 2);
  _Float16* Wqkv  = (_Float16*)alloc((size_t)kNQKV * kD * 2);
  _Float16* Wout  = (_Float16*)alloc((size_t)kD * kKOut * 2);
  float*    bcat  = (float*)alloc((size_t)kNQKV * 4);
  float*    bsum  = (float*)alloc((size_t)kD * 4);
  _Float16* ho    = (_Float16*)alloc((size_t)kS * kKOut * 2);
  _Float16* q_h   = (_Float16*)alloc((size_t)kS * kD * 2);
  _Float16* k_h   = (_Float16*)alloc((size_t)kS * kD * 2);
  _Float16* v_h   = (_Float16*)alloc((size_t)kS * kD * 2);
  _Float16* v_t   = (_Float16*)alloc((size_t)kS * kD * 2);

  // weight transposes (+fp16 convert): dst[n][k]
  wtrans_kernel<<<dim3(kF / 32, kD / 32), 256, 0, stream>>>(w_in, Wqkv, kF, kD, 0, 0);
  wtrans_kernel<<<dim3(kD / 32, kD / 32), 256, 0, stream>>>(wq, Wqkv, kD, kD, kF, 0);
  wtrans_kernel<<<dim3(kD / 32, kD / 32), 256, 0, stream>>>(wk, Wqkv, kD, kD, kF + kD, 0);
  wtrans_kernel<<<dim3(kD / 32, kD / 32), 256, 0, stream>>>(wv, Wqkv, kD, kD, kF + 2 * kD, 0);
  wtrans_kernel<<<dim3(kD / 32, kF / 32), 256, 0, stream>>>(w_mo, Wout, kD, kKOut, 0, 0);
  wtrans_kernel<<<dim3(kD / 32, kD / 32), 256, 0, stream>>>(w_ao, Wout, kD, kKOut, 0, kF);

  biasprep_kernel<<<(kNQKV + kD + 255) / 256, 256, 0, stream>>>(
      b_in, bq, bk, bv, b_mo, b_ao, bcat, bsum);

  ln_kernel<<<kS, 256, 0, stream>>>(x, ln_scale, ln_bias, xn);

  gemm_qkvin<<<dim3(kS / 128, kNQKV / 128), 256, 0, stream>>>(
      xn, Wqkv, bcat, ho, q_h, k_h, v_h);

  qknorm_kernel<<<kS * kH / 4, 256, 0, stream>>>(q_h, qn_scale, 0.125f);  // fold 1/sqrt(64)
  qknorm_kernel<<<kS * kH / 4, 256, 0, stream>>>(k_h, kn_scale, 1.0f);

  htrans_kernel<<<dim3(kD / 32, kS / 32), 256, 0, stream>>>(v_h, v_t, kS, kD);

  fattn_kernel<<<dim3(32, kH), 256, 0, stream>>>(q_h, k_h, v_t, ho);

  gemm_out<<<dim3(kS / 128, kD / 64), 256, 0, stream>>>(ho, Wout, bsum, x, out);
}

// Round 5
// 494.498 us; speedup vs baseline: 11.7381x; 1.0589x over previous
//
#include <hip/hip_runtime.h>
#include <hip/hip_fp16.h>

typedef _Float16 half8 __attribute__((ext_vector_type(8)));
typedef float floatx4 __attribute__((ext_vector_type(4)));

constexpr int kS = 4096;
constexpr int kD = 1024;
constexpr int kH = 16;
constexpr int kDh = 64;
constexpr int kF = 4096;
constexpr int kNQKV = kF + 3 * kD;   // 7168
constexpr int kKOut = kF + kD;       // 5120

__device__ __forceinline__ void async_ld16(const void* g, void* l) {
  __builtin_amdgcn_global_load_lds(
      (const __attribute__((address_space(1))) void*)g,
      (__attribute__((address_space(3))) void*)l, 16, 0, 0);
}

// ---------------------------------------------------------------- weight transpose + fp32->fp16
__global__ __launch_bounds__(256) void wtrans_kernel(
    const float* __restrict__ src, _Float16* __restrict__ dst,
    int N, int dldk, int noff, int koff) {
  __shared__ float t[32][33];
  const int tid = threadIdx.x;
  const int n0 = blockIdx.x * 32, k0 = blockIdx.y * 32;
#pragma unroll
  for (int i = 0; i < 4; ++i) {
    const int kl = (tid >> 5) + i * 8, nl = tid & 31;
    t[kl][nl] = src[(size_t)(k0 + kl) * N + n0 + nl];
  }
  __syncthreads();
#pragma unroll
  for (int i = 0; i < 4; ++i) {
    const int nl = (tid >> 5) + i * 8, kl = tid & 31;
    dst[(size_t)(noff + n0 + nl) * dldk + koff + k0 + kl] = (_Float16)t[kl][nl];
  }
}

// fp16 transpose: src [R][C] -> dst [C][R]
__global__ __launch_bounds__(256) void htrans_kernel(
    const _Float16* __restrict__ src, _Float16* __restrict__ dst, int R, int C) {
  __shared__ _Float16 t[32][34];
  const int tid = threadIdx.x;
  const int c0 = blockIdx.x * 32, r0 = blockIdx.y * 32;
#pragma unroll
  for (int i = 0; i < 4; ++i) {
    const int rl = (tid >> 5) + i * 8, cl = tid & 31;
    t[rl][cl] = src[(size_t)(r0 + rl) * C + c0 + cl];
  }
  __syncthreads();
#pragma unroll
  for (int i = 0; i < 4; ++i) {
    const int cl = (tid >> 5) + i * 8, rl = tid & 31;
    dst[(size_t)(c0 + cl) * R + r0 + rl] = t[rl][cl];
  }
}

// ---------------------------------------------------------------- bias prep
__global__ __launch_bounds__(256) void biasprep_kernel(
    const float* b_in, const float* bq, const float* bk, const float* bv,
    const float* b_mo, const float* b_ao, float* bcat, float* bsum) {
  const int i = blockIdx.x * 256 + threadIdx.x;
  if (i < kF) bcat[i] = b_in[i];
  else if (i < kF + kD) bcat[i] = bq[i - kF];
  else if (i < kF + 2 * kD) bcat[i] = bk[i - kF - kD];
  else if (i < kNQKV) bcat[i] = bv[i - kF - 2 * kD];
  else if (i < kNQKV + kD) bsum[i - kNQKV] = b_mo[i - kNQKV] + b_ao[i - kNQKV];
}

// ---------------------------------------------------------------- LayerNorm (D=1024) -> fp16
__global__ __launch_bounds__(256) void ln_kernel(
    const float* __restrict__ x, const float* __restrict__ scale,
    const float* __restrict__ bias, _Float16* __restrict__ xn) {
  const int row = blockIdx.x;
  const int tid = threadIdx.x;
  const float* xr = x + (size_t)row * kD;
  float v[4];
  float s = 0.f, sq = 0.f;
#pragma unroll
  for (int i = 0; i < 4; ++i) {
    v[i] = xr[tid + 256 * i];
    s += v[i];
    sq += v[i] * v[i];
  }
  for (int off = 32; off; off >>= 1) {
    s += __shfl_xor(s, off);
    sq += __shfl_xor(sq, off);
  }
  __shared__ float red[8];
  const int wv = tid >> 6;
  if ((tid & 63) == 0) { red[wv] = s; red[wv + 4] = sq; }
  __syncthreads();
  s = red[0] + red[1] + red[2] + red[3];
  sq = red[4] + red[5] + red[6] + red[7];
  const float mean = s * (1.0f / kD);
  const float var = sq * (1.0f / kD) - mean * mean;
  const float rstd = rsqrtf(var + 1e-6f);
#pragma unroll
  for (int i = 0; i < 4; ++i) {
    int d = tid + 256 * i;
    xn[(size_t)row * kD + d] = (_Float16)((v[i] - mean) * rstd * scale[d] + bias[d]);
  }
}

// ---------------------------------------------------------------- per-head qk LayerNorm
__global__ __launch_bounds__(256) void qknorm_kernel(
    _Float16* __restrict__ t, const float* __restrict__ scale, float smul) {
  const int row = (blockIdx.x << 2) + (threadIdx.x >> 6);
  const int lane = threadIdx.x & 63;
  _Float16* tr = t + (size_t)row * kDh;
  const float val = (float)tr[lane];
  float s = val;
  for (int off = 32; off; off >>= 1) s += __shfl_xor(s, off);
  const float mean = s * (1.0f / kDh);
  const float dv = val - mean;
  float sq = dv * dv;
  for (int off = 32; off; off >>= 1) sq += __shfl_xor(sq, off);
  const float rstd = rsqrtf(sq * (1.0f / kDh) + 1e-6f);
  tr[lane] = (_Float16)(dv * rstd * scale[lane] * smul);
}

// fast tanh-gelu: 0.5x(1+tanh z) = x*u/(1+u), u = e^{2z} = exp2(2*log2e*z)
__device__ __forceinline__ float fast_gelu(float xv) {
  const float z = 0.7978845608028654f * (xv + 0.044715f * xv * xv * xv);
  const float u = exp2f(fminf(2.885390081777927f * z, 80.0f));
  return xv * u / (1.0f + u);
}

// ---------------------------------------------------------------- fused QKV+MLP-in GEMM
__global__ __launch_bounds__(256) void gemm_qkvin(
    const _Float16* __restrict__ A, const _Float16* __restrict__ Bp,
    const float* __restrict__ bcat, _Float16* __restrict__ ho,
    _Float16* __restrict__ q, _Float16* __restrict__ k, _Float16* __restrict__ v) {
  __shared__ alignas(16) _Float16 Ts[16 * 512];
  _Float16* As = Ts;
  _Float16* Bs = Ts + 8 * 512;

  const int tid = threadIdx.x;
  const int lane = tid & 63;
  const int wave = tid >> 6;
  const int wm = (wave >> 1) * 64;
  const int wn = (wave & 1) * 64;
  const int m0 = blockIdx.x * 128;
  const int n0 = blockIdx.y * 128;
  const int lrow = lane & 15;
  const int quad = lane >> 4;

  floatx4 acc[4][4] = {};

  for (int k0 = 0; k0 < kD; k0 += 32) {
    __syncthreads();
#pragma unroll
    for (int i = 0; i < 4; ++i) {
      const int chunk = wave * 4 + i;
      const int r = ((chunk & 7) << 4) + (lane >> 2);
      const int csrc = ((lane & 3) ^ ((r >> 1) & 3)) << 3;
      const _Float16* src = (chunk < 8)
          ? A + (size_t)(m0 + r) * kD + k0 + csrc
          : Bp + (size_t)(n0 + r) * kD + k0 + csrc;
      async_ld16(src, Ts + chunk * 512);
    }
    __syncthreads();

    half8 af[4], bf[4];
#pragma unroll
    for (int i = 0; i < 4; ++i) {
      const int ra = wm + i * 16 + lrow;
      const int rb = wn + i * 16 + lrow;
      af[i] = *reinterpret_cast<const half8*>(&As[ra * 32 + ((quad ^ ((ra >> 1) & 3)) << 3)]);
      bf[i] = *reinterpret_cast<const half8*>(&Bs[rb * 32 + ((quad ^ ((rb >> 1) & 3)) << 3)]);
    }
#pragma unroll
    for (int i = 0; i < 4; ++i)
#pragma unroll
      for (int j = 0; j < 4; ++j)
        acc[i][j] = __builtin_amdgcn_mfma_f32_16x16x32_f16(af[i], bf[j], acc[i][j], 0, 0, 0);
  }

#pragma unroll
  for (int i = 0; i < 4; ++i) {
    const int gm = m0 + wm + i * 16 + quad * 4;
#pragma unroll
    for (int j = 0; j < 4; ++j) {
      const int gn = n0 + wn + j * 16 + lrow;
      const float bn = bcat[gn];
#pragma unroll
      for (int r = 0; r < 4; ++r) {
        float vv = acc[i][j][r] + bn;
        if (gn < kF) {
          ho[(size_t)(gm + r) * kKOut + gn] = (_Float16)fast_gelu(vv);
        } else {
          const int reg = gn - kF;
          _Float16* dst = (reg < kD) ? q : (reg < 2 * kD) ? k : v;
          dst[(size_t)(gm + r) * kD + (reg & (kD - 1))] = (_Float16)vv;
        }
      }
    }
  }
}

// ---------------------------------------------------------------- out init: out = x + bsum
__global__ __launch_bounds__(256) void initout_kernel(
    const float* __restrict__ x, const float* __restrict__ bsum,
    float* __restrict__ out) {
  const int i = blockIdx.x * 256 + threadIdx.x;
  out[i] = x[i] + bsum[i & (kD - 1)];
}

// ---------------------------------------------------------------- fused out GEMM, 128x128 tile, split-K=2, atomic accumulate
__global__ __launch_bounds__(256) void gemm_out(
    const _Float16* __restrict__ A, const _Float16* __restrict__ Bp,
    float* __restrict__ out) {
  __shared__ alignas(16) _Float16 Ts[16 * 512];
  _Float16* As = Ts;
  _Float16* Bs = Ts + 8 * 512;

  const int tid = threadIdx.x;
  const int lane = tid & 63;
  const int wave = tid >> 6;
  const int wm = (wave >> 1) * 64;
  const int wn = (wave & 1) * 64;
  const int m0 = blockIdx.x * 128;
  const int n0 = blockIdx.y * 128;
  const int kbeg = blockIdx.z * (kKOut / 2);
  const int lrow = lane & 15;
  const int quad = lane >> 4;

  floatx4 acc[4][4] = {};

  for (int k0 = kbeg; k0 < kbeg + kKOut / 2; k0 += 32) {
    __syncthreads();
#pragma unroll
    for (int i = 0; i < 4; ++i) {
      const int chunk = wave * 4 + i;
      const int r = ((chunk & 7) << 4) + (lane >> 2);
      const int csrc = ((lane & 3) ^ ((r >> 1) & 3)) << 3;
      const _Float16* src = (chunk < 8)
          ? A + (size_t)(m0 + r) * kKOut + k0 + csrc
          : Bp + (size_t)(n0 + r) * kKOut + k0 + csrc;
      async_ld16(src, Ts + chunk * 512);
    }
    __syncthreads();

    half8 af[4], bf[4];
#pragma unroll
    for (int i = 0; i < 4; ++i) {
      const int ra = wm + i * 16 + lrow;
      const int rb = wn + i * 16 + lrow;
      af[i] = *reinterpret_cast<const half8*>(&As[ra * 32 + ((quad ^ ((ra >> 1) & 3)) << 3)]);
      bf[i] = *reinterpret_cast<const half8*>(&Bs[rb * 32 + ((quad ^ ((rb >> 1) & 3)) << 3)]);
    }
#pragma unroll
    for (int i = 0; i < 4; ++i)
#pragma unroll
      for (int j = 0; j < 4; ++j)
        acc[i][j] = __builtin_amdgcn_mfma_f32_16x16x32_f16(af[i], bf[j], acc[i][j], 0, 0, 0);
  }

#pragma unroll
  for (int i = 0; i < 4; ++i) {
    const int gm = m0 + wm + i * 16 + quad * 4;
#pragma unroll
    for (int j = 0; j < 4; ++j) {
      const int gn = n0 + wn + j * 16 + lrow;
#pragma unroll
      for (int r = 0; r < 4; ++r)
        atomicAdd(out + (size_t)(gm + r) * kD + gn, acc[i][j][r]);
    }
  }
}

// ---------------------------------------------------------------- zero accumulators
__global__ __launch_bounds__(256) void zeroacc_kernel(float* __restrict__ p, int n) {
  const int i = blockIdx.x * 256 + threadIdx.x;
  if (i < n) p[i] = 0.f;
}

// ---------------------------------------------------------------- flash attention v3: no-max softmax, pairs + k-split
// Scores bounded: |q|=|k|=8 after LN => s=q.k/8 in [-8,8]. Q pre-scaled by
// 0.125*log2e at qknorm => p = exp2(s' - 8*log2e) <= 1. No running max,
// per-lane l, O/l combine additively across splits via atomicAdd.
__global__ __launch_bounds__(256) void fattn_kernel(
    const _Float16* __restrict__ Q, const _Float16* __restrict__ K,
    const _Float16* __restrict__ Vt, float* __restrict__ Oacc,
    float* __restrict__ Lacc) {
  __shared__ alignas(16) _Float16 Qs[64 * 64];
  __shared__ alignas(16) _Float16 Ks[64 * 64];
  __shared__ alignas(16) _Float16 Vs[64 * 64];
  __shared__ alignas(16) _Float16 Ps[64 * 72];

  const int tid = threadIdx.x;
  const int lane = tid & 63;
  const int wave = tid >> 6;
  const int lrow = lane & 15;
  const int quad = lane >> 4;
  const int h = blockIdx.y;
  const int pair = blockIdx.x;
  const int split = blockIdx.z;

  const int rs = lane >> 3;
  const int cs = lane & 7;
  constexpr float kOff = 11.5415603f;  // 8*log2(e)

  for (int pass = 0; pass < 2; ++pass) {
    const int qtile = pass ? (63 - pair) : pair;
    const int qbase = qtile * 64;

    __syncthreads();
#pragma unroll
    for (int i = 0; i < 2; ++i) {
      const int chunk = wave * 2 + i;
      const int r = chunk * 8 + rs;
      async_ld16(Q + (size_t)(qbase + r) * kD + h * kDh + ((cs ^ (r & 7)) << 3),
                 Qs + chunk * 512);
    }
    __syncthreads();

    half8 qf[2];
#pragma unroll
    for (int kt = 0; kt < 2; ++kt)
      qf[kt] = *reinterpret_cast<const half8*>(
          &Qs[(wave * 16 + lrow) * 64 + (((kt * 4 + quad) ^ (lrow & 7)) << 3)]);

    float lst[4] = {0.f, 0.f, 0.f, 0.f};
    floatx4 oacc[4] = {};
    const int qw = qbase + wave * 16;

    for (int t = split; t <= qtile; t += 2) {
      const int k0 = t * 64;
      __syncthreads();
#pragma unroll
      for (int i = 0; i < 4; ++i) {
        const int id = wave * 4 + i;
        if (id < 8) {
          const int r = id * 8 + rs;
          async_ld16(K + (size_t)(k0 + r) * kD + h * kDh + ((cs ^ (r & 7)) << 3),
                     Ks + id * 512);
        } else {
          const int c = id - 8;
          const int r = c * 8 + rs;
          async_ld16(Vt + (size_t)(h * kDh + r) * kS + k0 + ((cs ^ (r & 7)) << 3),
                     Vs + c * 512);
        }
      }
      __syncthreads();

      const bool diag = (t == qtile);

      floatx4 sacc[4] = {};
#pragma unroll
      for (int jt = 0; jt < 4; ++jt) {
        if (diag && jt > wave) continue;
#pragma unroll
        for (int kt = 0; kt < 2; ++kt) {
          const int rb = jt * 16 + lrow;
          half8 bfk = *reinterpret_cast<const half8*>(
              &Ks[rb * 64 + (((kt * 4 + quad) ^ (lrow & 7)) << 3)]);
          sacc[jt] = __builtin_amdgcn_mfma_f32_16x16x32_f16(qf[kt], bfk, sacc[jt], 0, 0, 0);
        }
      }

      if (diag) {
#pragma unroll
        for (int jt = 0; jt < 4; ++jt) {
          const int kg = k0 + jt * 16 + lrow;
#pragma unroll
          for (int r = 0; r < 4; ++r)
            if (kg > qw + quad * 4 + r) sacc[jt][r] = -1e30f;
        }
      }

      // p = exp2(s' - 8log2e), per-lane l accumulation (no max/rescale)
#pragma unroll
      for (int jt = 0; jt < 4; ++jt)
#pragma unroll
        for (int r = 0; r < 4; ++r) {
          const float p = exp2f(sacc[jt][r] - kOff);
          sacc[jt][r] = p;
          lst[r] += p;
        }

      // P: C-layout -> LDS (wave-private rows)
#pragma unroll
      for (int jt = 0; jt < 4; ++jt)
#pragma unroll
        for (int r = 0; r < 4; ++r)
          Ps[(wave * 16 + quad * 4 + r) * 72 + jt * 16 + lrow] = (_Float16)sacc[jt][r];

      const int ktmax = (diag && wave < 2) ? 1 : 2;
      for (int kt = 0; kt < ktmax; ++kt) {
        half8 pf = *reinterpret_cast<const half8*>(
            &Ps[(wave * 16 + lrow) * 72 + (kt * 4 + quad) * 8]);
#pragma unroll
        for (int jt = 0; jt < 4; ++jt) {
          const int rb = jt * 16 + lrow;
          half8 vf = *reinterpret_cast<const half8*>(
              &Vs[rb * 64 + (((kt * 4 + quad) ^ (lrow & 7)) << 3)]);
          oacc[jt] = __builtin_amdgcn_mfma_f32_16x16x32_f16(pf, vf, oacc[jt], 0, 0, 0);
        }
      }
    }

    // epilogue: reduce l over the 16 columns, atomic-accumulate partials
#pragma unroll
    for (int r = 0; r < 4; ++r) {
#pragma unroll
      for (int off = 8; off; off >>= 1) lst[r] += __shfl_xor(lst[r], off);
    }
#pragma unroll
    for (int r = 0; r < 4; ++r) {
      const int qg = qw + quad * 4 + r;
      if (lrow == 0) atomicAdd(Lacc + qg * kH + h, lst[r]);
#pragma unroll
      for (int jt = 0; jt < 4; ++jt)
        atomicAdd(Oacc + ((size_t)qg * kH + h) * kDh + jt * 16 + lrow, oacc[jt][r]);
    }
  }
}

// ---------------------------------------------------------------- normalize: ho attn columns = Oacc / Lacc
__global__ __launch_bounds__(256) void norm_kernel(
    const float* __restrict__ Oacc, const float* __restrict__ Lacc,
    _Float16* __restrict__ ho) {
  const int idx = blockIdx.x * 256 + threadIdx.x;  // < S*D
  const int q = idx >> 10, rem = idx & 1023;
  const float l = Lacc[(q << 4) + (rem >> 6)];
  ho[(size_t)q * kKOut + kF + rem] = (_Float16)(Oacc[idx] / l);
}

// ---------------------------------------------------------------- launch
extern "C" void kernel_launch(void* const* d_in, const int* in_sizes, int n_in,
                              void* d_out, int out_size, void* d_ws, size_t ws_size,
                              hipStream_t stream) {
  const float* x        = (const float*)d_in[0];
  const float* ln_scale = (const float*)d_in[2];
  const float* ln_bias  = (const float*)d_in[3];
  const float* w_in     = (const float*)d_in[4];
  const float* b_in     = (const float*)d_in[5];
  const float* wq       = (const float*)d_in[6];
  const float* bq       = (const float*)d_in[7];
  const float* wk       = (const float*)d_in[8];
  const float* bk       = (const float*)d_in[9];
  const float* wv       = (const float*)d_in[10];
  const float* bv       = (const float*)d_in[11];
  const float* qn_scale = (const float*)d_in[12];
  const float* kn_scale = (const float*)d_in[13];
  const float* w_mo     = (const float*)d_in[14];
  const float* b_mo     = (const float*)d_in[15];
  const float* w_ao     = (const float*)d_in[16];
  const float* b_ao     = (const float*)d_in[17];
  float* out = (float*)d_out;

  char* ws = (char*)d_ws;
  size_t off = 0;
  auto alloc = [&](size_t bytes) { char* p = ws + off; off += bytes; return p; };
  // alias zone: xn+Wqkv (23.0 MB) dead after gemm_qkvin; Oacc/Lacc overlay (17.0 MB)
  char* zone = (char*)alloc((size_t)kS * kD * 2 + (size_t)kNQKV * kD * 2);
  _Float16* xn   = (_Float16*)zone;
  _Float16* Wqkv = (_Float16*)(zone + (size_t)kS * kD * 2);
  float* Oacc = (float*)zone;                                    // 16 MB
  float* Lacc = (float*)(zone + (size_t)kS * kD * 4);            // 256 KB
  _Float16* Wout = (_Float16*)alloc((size_t)kD * kKOut * 2);
  float*    bcat = (float*)alloc((size_t)kNQKV * 4);
  float*    bsum = (float*)alloc((size_t)kD * 4);
  _Float16* ho   = (_Float16*)alloc((size_t)kS * kKOut * 2);
  _Float16* q_h  = (_Float16*)alloc((size_t)kS * kD * 2);
  _Float16* k_h  = (_Float16*)alloc((size_t)kS * kD * 2);
  _Float16* v_h  = (_Float16*)alloc((size_t)kS * kD * 2);
  _Float16* v_t  = (_Float16*)alloc((size_t)kS * kD * 2);

  wtrans_kernel<<<dim3(kF / 32, kD / 32), 256, 0, stream>>>(w_in, Wqkv, kF, kD, 0, 0);
  wtrans_kernel<<<dim3(kD / 32, kD / 32), 256, 0, stream>>>(wq, Wqkv, kD, kD, kF, 0);
  wtrans_kernel<<<dim3(kD / 32, kD / 32), 256, 0, stream>>>(wk, Wqkv, kD, kD, kF + kD, 0);
  wtrans_kernel<<<dim3(kD / 32, kD / 32), 256, 0, stream>>>(wv, Wqkv, kD, kD, kF + 2 * kD, 0);
  wtrans_kernel<<<dim3(kD / 32, kF / 32), 256, 0, stream>>>(w_mo, Wout, kD, kKOut, 0, 0);
  wtrans_kernel<<<dim3(kD / 32, kD / 32), 256, 0, stream>>>(w_ao, Wout, kD, kKOut, 0, kF);

  biasprep_kernel<<<(kNQKV + kD + 255) / 256, 256, 0, stream>>>(
      b_in, bq, bk, bv, b_mo, b_ao, bcat, bsum);

  ln_kernel<<<kS, 256, 0, stream>>>(x, ln_scale, ln_bias, xn);

  gemm_qkvin<<<dim3(kS / 128, kNQKV / 128), 256, 0, stream>>>(
      xn, Wqkv, bcat, ho, q_h, k_h, v_h);

  // fold 0.125 * log2(e) into q so fattn works in exp2 domain
  qknorm_kernel<<<kS * kH / 4, 256, 0, stream>>>(q_h, qn_scale, 0.18033688f);
  qknorm_kernel<<<kS * kH / 4, 256, 0, stream>>>(k_h, kn_scale, 1.0f);

  htrans_kernel<<<dim3(kD / 32, kS / 32), 256, 0, stream>>>(v_h, v_t, kS, kD);

  // zero Oacc+Lacc (overlays dead xn/Wqkv)
  zeroacc_kernel<<<(kS * kD + kS * kH + 255) / 256, 256, 0, stream>>>(
      Oacc, kS * kD + kS * kH);

  fattn_kernel<<<dim3(32, kH, 2), 256, 0, stream>>>(q_h, k_h, v_t, Oacc, Lacc);

  norm_kernel<<<kS * kD / 256, 256, 0, stream>>>(Oacc, Lacc, ho);

  initout_kernel<<<kS * kD / 256, 256, 0, stream>>>(x, bsum, out);
  gemm_out<<<dim3(kS / 128, kD / 128, 2), 256, 0, stream>>>(ho, Wout, out);
}

// Round 6
// 494.062 us; speedup vs baseline: 11.7485x; 1.0009x over previous
//
#include <hip/hip_runtime.h>
#include <hip/hip_fp16.h>

typedef _Float16 half8 __attribute__((ext_vector_type(8)));
typedef float floatx4 __attribute__((ext_vector_type(4)));

constexpr int kS = 4096;
constexpr int kD = 1024;
constexpr int kH = 16;
constexpr int kDh = 64;
constexpr int kF = 4096;
constexpr int kNQKV = kF + 3 * kD;   // 7168
constexpr int kKOut = kF + kD;       // 5120

__device__ __forceinline__ void async_ld16(const void* g, void* l) {
  __builtin_amdgcn_global_load_lds(
      (const __attribute__((address_space(1))) void*)g,
      (__attribute__((address_space(3))) void*)l, 16, 0, 0);
}

// ---------------------------------------------------------------- all weight transposes in one launch
// 12288 tile-blocks: w_in 4096 | wq 1024 | wk 1024 | wv 1024 | w_mo 4096 | w_ao 1024
__global__ __launch_bounds__(256) void wtrans_all(
    const float* __restrict__ w_in, const float* __restrict__ wq,
    const float* __restrict__ wk, const float* __restrict__ wv,
    const float* __restrict__ w_mo, const float* __restrict__ w_ao,
    _Float16* __restrict__ Wqkv, _Float16* __restrict__ Wout) {
  __shared__ float t[32][33];
  int id = blockIdx.x;
  const float* src; _Float16* dst; int N, ldk, noff, koff, nt, kt;
  if (id < 4096)       { src = w_in; dst = Wqkv; N = kF; ldk = kD; noff = 0;        koff = 0;  nt = id & 127; kt = id >> 7; }
  else if (id < 5120)  { id -= 4096; src = wq;  dst = Wqkv; N = kD; ldk = kD; noff = kF;       koff = 0;  nt = id & 31; kt = id >> 5; }
  else if (id < 6144)  { id -= 5120; src = wk;  dst = Wqkv; N = kD; ldk = kD; noff = kF + kD;  koff = 0;  nt = id & 31; kt = id >> 5; }
  else if (id < 7168)  { id -= 6144; src = wv;  dst = Wqkv; N = kD; ldk = kD; noff = kF + 2*kD; koff = 0; nt = id & 31; kt = id >> 5; }
  else if (id < 11264) { id -= 7168; src = w_mo; dst = Wout; N = kD; ldk = kKOut; noff = 0;    koff = 0;  nt = id & 31; kt = id >> 5; }
  else                 { id -= 11264; src = w_ao; dst = Wout; N = kD; ldk = kKOut; noff = 0;   koff = kF; nt = id & 31; kt = id >> 5; }
  const int tid = threadIdx.x;
  const int n0 = nt * 32, k0 = kt * 32;
#pragma unroll
  for (int i = 0; i < 4; ++i) {
    const int kl = (tid >> 5) + i * 8, nl = tid & 31;
    t[kl][nl] = src[(size_t)(k0 + kl) * N + n0 + nl];
  }
  __syncthreads();
#pragma unroll
  for (int i = 0; i < 4; ++i) {
    const int nl = (tid >> 5) + i * 8, kl = tid & 31;
    dst[(size_t)(noff + n0 + nl) * ldk + koff + k0 + kl] = (_Float16)t[kl][nl];
  }
}

// fp16 transpose: src [R][C] -> dst [C][R]
__global__ __launch_bounds__(256) void htrans_kernel(
    const _Float16* __restrict__ src, _Float16* __restrict__ dst, int R, int C) {
  __shared__ _Float16 t[32][34];
  const int tid = threadIdx.x;
  const int c0 = blockIdx.x * 32, r0 = blockIdx.y * 32;
#pragma unroll
  for (int i = 0; i < 4; ++i) {
    const int rl = (tid >> 5) + i * 8, cl = tid & 31;
    t[rl][cl] = src[(size_t)(r0 + rl) * C + c0 + cl];
  }
  __syncthreads();
#pragma unroll
  for (int i = 0; i < 4; ++i) {
    const int cl = (tid >> 5) + i * 8, rl = tid & 31;
    dst[(size_t)(c0 + cl) * R + r0 + rl] = t[rl][cl];
  }
}

// ---------------------------------------------------------------- bias prep
__global__ __launch_bounds__(256) void biasprep_kernel(
    const float* b_in, const float* bq, const float* bk, const float* bv,
    const float* b_mo, const float* b_ao, float* bcat, float* bsum) {
  const int i = blockIdx.x * 256 + threadIdx.x;
  if (i < kF) bcat[i] = b_in[i];
  else if (i < kF + kD) bcat[i] = bq[i - kF];
  else if (i < kF + 2 * kD) bcat[i] = bk[i - kF - kD];
  else if (i < kNQKV) bcat[i] = bv[i - kF - 2 * kD];
  else if (i < kNQKV + kD) bsum[i - kNQKV] = b_mo[i - kNQKV] + b_ao[i - kNQKV];
}

// ---------------------------------------------------------------- LayerNorm (D=1024) -> fp16
__global__ __launch_bounds__(256) void ln_kernel(
    const float* __restrict__ x, const float* __restrict__ scale,
    const float* __restrict__ bias, _Float16* __restrict__ xn) {
  const int row = blockIdx.x;
  const int tid = threadIdx.x;
  const float* xr = x + (size_t)row * kD;
  float v[4];
  float s = 0.f, sq = 0.f;
#pragma unroll
  for (int i = 0; i < 4; ++i) {
    v[i] = xr[tid + 256 * i];
    s += v[i];
    sq += v[i] * v[i];
  }
  for (int off = 32; off; off >>= 1) {
    s += __shfl_xor(s, off);
    sq += __shfl_xor(sq, off);
  }
  __shared__ float red[8];
  const int wv = tid >> 6;
  if ((tid & 63) == 0) { red[wv] = s; red[wv + 4] = sq; }
  __syncthreads();
  s = red[0] + red[1] + red[2] + red[3];
  sq = red[4] + red[5] + red[6] + red[7];
  const float mean = s * (1.0f / kD);
  const float var = sq * (1.0f / kD) - mean * mean;
  const float rstd = rsqrtf(var + 1e-6f);
#pragma unroll
  for (int i = 0; i < 4; ++i) {
    int d = tid + 256 * i;
    xn[(size_t)row * kD + d] = (_Float16)((v[i] - mean) * rstd * scale[d] + bias[d]);
  }
}

// fast tanh-gelu
__device__ __forceinline__ float fast_gelu(float xv) {
  const float z = 0.7978845608028654f * (xv + 0.044715f * xv * xv * xv);
  const float u = exp2f(fminf(2.885390081777927f * z, 80.0f));
  return xv * u / (1.0f + u);
}

// ---------------------------------------------------------------- fused QKV+MLP-in GEMM (+fused qk-LayerNorm)
__global__ __launch_bounds__(256) void gemm_qkvin(
    const _Float16* __restrict__ A, const _Float16* __restrict__ Bp,
    const float* __restrict__ bcat, const float* __restrict__ qn_scale,
    const float* __restrict__ kn_scale, _Float16* __restrict__ ho,
    _Float16* __restrict__ q, _Float16* __restrict__ k, _Float16* __restrict__ v) {
  __shared__ alignas(16) _Float16 Ts[16 * 512];
  _Float16* As = Ts;
  _Float16* Bs = Ts + 8 * 512;

  const int tid = threadIdx.x;
  const int lane = tid & 63;
  const int wave = tid >> 6;
  const int wm = (wave >> 1) * 64;
  const int wn = (wave & 1) * 64;
  const int m0 = blockIdx.x * 128;
  const int n0 = blockIdx.y * 128;
  const int lrow = lane & 15;
  const int quad = lane >> 4;

  floatx4 acc[4][4] = {};

  for (int k0 = 0; k0 < kD; k0 += 32) {
    __syncthreads();
#pragma unroll
    for (int i = 0; i < 4; ++i) {
      const int chunk = wave * 4 + i;
      const int r = ((chunk & 7) << 4) + (lane >> 2);
      const int csrc = ((lane & 3) ^ ((r >> 1) & 3)) << 3;
      const _Float16* src = (chunk < 8)
          ? A + (size_t)(m0 + r) * kD + k0 + csrc
          : Bp + (size_t)(n0 + r) * kD + k0 + csrc;
      async_ld16(src, Ts + chunk * 512);
    }
    __syncthreads();

    half8 af[4], bf[4];
#pragma unroll
    for (int i = 0; i < 4; ++i) {
      const int ra = wm + i * 16 + lrow;
      const int rb = wn + i * 16 + lrow;
      af[i] = *reinterpret_cast<const half8*>(&As[ra * 32 + ((quad ^ ((ra >> 1) & 3)) << 3)]);
      bf[i] = *reinterpret_cast<const half8*>(&Bs[rb * 32 + ((quad ^ ((rb >> 1) & 3)) << 3)]);
    }
#pragma unroll
    for (int i = 0; i < 4; ++i)
#pragma unroll
      for (int j = 0; j < 4; ++j)
        acc[i][j] = __builtin_amdgcn_mfma_f32_16x16x32_f16(af[i], bf[j], acc[i][j], 0, 0, 0);
  }

  const int nblk = n0 + wn;  // wave col base; region-uniform per wave
  if (nblk < kF) {           // gelu -> ho
#pragma unroll
    for (int i = 0; i < 4; ++i) {
      const int gm = m0 + wm + i * 16 + quad * 4;
#pragma unroll
      for (int j = 0; j < 4; ++j) {
        const int gn = nblk + j * 16 + lrow;
        const float bn = bcat[gn];
#pragma unroll
        for (int r = 0; r < 4; ++r)
          ho[(size_t)(gm + r) * kKOut + gn] = (_Float16)fast_gelu(acc[i][j][r] + bn);
      }
    }
  } else if (nblk >= kF + 2 * kD) {  // v plain
#pragma unroll
    for (int i = 0; i < 4; ++i) {
      const int gm = m0 + wm + i * 16 + quad * 4;
#pragma unroll
      for (int j = 0; j < 4; ++j) {
        const int gn = nblk + j * 16 + lrow;
        const float bn = bcat[gn];
#pragma unroll
        for (int r = 0; r < 4; ++r)
          v[(size_t)(gm + r) * kD + ((gn - kF) & (kD - 1))] = (_Float16)(acc[i][j][r] + bn);
      }
    }
  } else {  // q or k: fused per-head LayerNorm (wave's 64 cols = one head)
    const bool isq = nblk < kF + kD;
    const float* nsc = isq ? qn_scale : kn_scale;
    const float sm = isq ? 0.18033688f : 1.0f;  // q: fold 0.125*log2e
    _Float16* dst = isq ? q : k;
    const int col0 = (nblk - kF) & (kD - 1);
    float bj[4];
#pragma unroll
    for (int j = 0; j < 4; ++j) bj[j] = bcat[nblk + j * 16 + lrow];
#pragma unroll
    for (int i = 0; i < 4; ++i) {
      const int gm = m0 + wm + i * 16 + quad * 4;
#pragma unroll
      for (int r = 0; r < 4; ++r) {
        float vals[4], s1 = 0.f, s2 = 0.f;
#pragma unroll
        for (int j = 0; j < 4; ++j) {
          const float vv = acc[i][j][r] + bj[j];
          vals[j] = vv; s1 += vv; s2 += vv * vv;
        }
#pragma unroll
        for (int off = 1; off <= 8; off <<= 1) {
          s1 += __shfl_xor(s1, off);
          s2 += __shfl_xor(s2, off);
        }
        const float mean = s1 * (1.0f / 64.0f);
        const float rstd = rsqrtf(s2 * (1.0f / 64.0f) - mean * mean + 1e-6f);
#pragma unroll
        for (int j = 0; j < 4; ++j) {
          const int d = j * 16 + lrow;
          dst[(size_t)(gm + r) * kD + col0 + d] =
              (_Float16)((vals[j] - mean) * rstd * nsc[d] * sm);
        }
      }
    }
  }
}

// ---------------------------------------------------------------- out init: out = x + bsum
__global__ __launch_bounds__(256) void initout_kernel(
    const float* __restrict__ x, const float* __restrict__ bsum,
    float* __restrict__ out) {
  const int i = blockIdx.x * 256 + threadIdx.x;
  out[i] = x[i] + bsum[i & (kD - 1)];
}

// ---------------------------------------------------------------- fused out GEMM, 128x128, split-K=2, atomic accumulate
__global__ __launch_bounds__(256) void gemm_out(
    const _Float16* __restrict__ A, const _Float16* __restrict__ Bp,
    float* __restrict__ out) {
  __shared__ alignas(16) _Float16 Ts[16 * 512];
  _Float16* As = Ts;
  _Float16* Bs = Ts + 8 * 512;

  const int tid = threadIdx.x;
  const int lane = tid & 63;
  const int wave = tid >> 6;
  const int wm = (wave >> 1) * 64;
  const int wn = (wave & 1) * 64;
  const int m0 = blockIdx.x * 128;
  const int n0 = blockIdx.y * 128;
  const int kbeg = blockIdx.z * (kKOut / 2);
  const int lrow = lane & 15;
  const int quad = lane >> 4;

  floatx4 acc[4][4] = {};

  for (int k0 = kbeg; k0 < kbeg + kKOut / 2; k0 += 32) {
    __syncthreads();
#pragma unroll
    for (int i = 0; i < 4; ++i) {
      const int chunk = wave * 4 + i;
      const int r = ((chunk & 7) << 4) + (lane >> 2);
      const int csrc = ((lane & 3) ^ ((r >> 1) & 3)) << 3;
      const _Float16* src = (chunk < 8)
          ? A + (size_t)(m0 + r) * kKOut + k0 + csrc
          : Bp + (size_t)(n0 + r) * kKOut + k0 + csrc;
      async_ld16(src, Ts + chunk * 512);
    }
    __syncthreads();

    half8 af[4], bf[4];
#pragma unroll
    for (int i = 0; i < 4; ++i) {
      const int ra = wm + i * 16 + lrow;
      const int rb = wn + i * 16 + lrow;
      af[i] = *reinterpret_cast<const half8*>(&As[ra * 32 + ((quad ^ ((ra >> 1) & 3)) << 3)]);
      bf[i] = *reinterpret_cast<const half8*>(&Bs[rb * 32 + ((quad ^ ((rb >> 1) & 3)) << 3)]);
    }
#pragma unroll
    for (int i = 0; i < 4; ++i)
#pragma unroll
      for (int j = 0; j < 4; ++j)
        acc[i][j] = __builtin_amdgcn_mfma_f32_16x16x32_f16(af[i], bf[j], acc[i][j], 0, 0, 0);
  }

#pragma unroll
  for (int i = 0; i < 4; ++i) {
    const int gm = m0 + wm + i * 16 + quad * 4;
#pragma unroll
    for (int j = 0; j < 4; ++j) {
      const int gn = n0 + wn + j * 16 + lrow;
#pragma unroll
      for (int r = 0; r < 4; ++r)
        atomicAdd(out + (size_t)(gm + r) * kD + gn, acc[i][j][r]);
    }
  }
}

// ---------------------------------------------------------------- zero accumulators
__global__ __launch_bounds__(256) void zeroacc_kernel(float* __restrict__ p, int n) {
  const int i = blockIdx.x * 256 + threadIdx.x;
  if (i < n) p[i] = 0.f;
}

// ---------------------------------------------------------------- flash attention v4: 128 q-rows/block, XCD-swizzled
// grid 768 (1D): xcd=id&7 -> heads {2x,2x+1} stay on one XCD (K/V 2MB <= 4MB L2).
// Block = (pair of 128-row q-tiles {p,31-p}) x head x split(3). No-max softmax
// (|s|<=8 bound after qk-LN), per-lane l, additive combination via atomicAdd.
__global__ __launch_bounds__(256) void fattn_kernel(
    const _Float16* __restrict__ Q, const _Float16* __restrict__ K,
    const _Float16* __restrict__ Vt, float* __restrict__ Oacc,
    float* __restrict__ Lacc) {
  __shared__ alignas(16) _Float16 Qs[128 * 64];  // 16 KB swizzled (c ^ (r&7))
  __shared__ alignas(16) _Float16 Ks[64 * 64];   // 8 KB rows=key
  __shared__ alignas(16) _Float16 Vs[64 * 64];   // 8 KB rows=dh
  __shared__ alignas(16) _Float16 Ps[128 * 72];  // 18 KB padded

  const int tid = threadIdx.x;
  const int lane = tid & 63;
  const int wave = tid >> 6;
  const int lrow = lane & 15;
  const int quad = lane >> 4;

  const int id = blockIdx.x;
  const int xcd = id & 7;
  const int idx = id >> 3;            // 0..95 per XCD
  const int h = (xcd << 1) | (idx & 1);
  const int rem = idx >> 1;           // 0..47
  const int pair = rem & 15;          // 16 pairs of 128-row tiles
  const int split = rem >> 4;         // 0..2

  const int rs = lane >> 3;
  const int cs = lane & 7;
  constexpr float kOff = 11.5415603f;  // 8*log2(e)

  for (int pass = 0; pass < 2; ++pass) {
    const int qtile = pass ? (31 - pair) : pair;
    const int qbase = qtile * 128;

    __syncthreads();
#pragma unroll
    for (int i = 0; i < 4; ++i) {  // Q: 16 chunks x 8 rows
      const int chunk = wave * 4 + i;
      const int r = chunk * 8 + rs;
      async_ld16(Q + (size_t)(qbase + r) * kD + h * kDh + ((cs ^ (r & 7)) << 3),
                 Qs + chunk * 512);
    }
    __syncthreads();

    half8 qf[2][2];
#pragma unroll
    for (int i = 0; i < 2; ++i)
#pragma unroll
      for (int kt = 0; kt < 2; ++kt) {
        const int row = wave * 32 + i * 16 + lrow;
        qf[i][kt] = *reinterpret_cast<const half8*>(
            &Qs[row * 64 + (((kt * 4 + quad) ^ (row & 7)) << 3)]);
      }

    float lst[2][4] = {};
    floatx4 oacc[2][4] = {};
    const int qw = qbase + wave * 32;
    const int tmax = 2 * qtile + 1;

    for (int t = split; t <= tmax; t += 3) {
      const int k0 = t * 64;
      __syncthreads();
#pragma unroll
      for (int i = 0; i < 4; ++i) {
        const int c2 = wave * 4 + i;
        if (c2 < 8) {
          const int r = c2 * 8 + rs;
          async_ld16(K + (size_t)(k0 + r) * kD + h * kDh + ((cs ^ (r & 7)) << 3),
                     Ks + c2 * 512);
        } else {
          const int c = c2 - 8;
          const int r = c * 8 + rs;
          async_ld16(Vt + (size_t)(h * kDh + r) * kS + k0 + ((cs ^ (r & 7)) << 3),
                     Vs + c * 512);
        }
      }
      __syncthreads();

      if (k0 > qw + 31) continue;  // whole wave above diagonal

      const bool diag = (k0 + 63 > qw);
      floatx4 sacc[2][4] = {};
#pragma unroll
      for (int jt = 0; jt < 4; ++jt) {
        if (diag && (k0 + jt * 16 > qw + 31)) continue;  // fully-masked block
#pragma unroll
        for (int kt = 0; kt < 2; ++kt) {
          const int rb = jt * 16 + lrow;
          half8 bfk = *reinterpret_cast<const half8*>(
              &Ks[rb * 64 + (((kt * 4 + quad) ^ (rb & 7)) << 3)]);
          sacc[0][jt] = __builtin_amdgcn_mfma_f32_16x16x32_f16(qf[0][kt], bfk, sacc[0][jt], 0, 0, 0);
          sacc[1][jt] = __builtin_amdgcn_mfma_f32_16x16x32_f16(qf[1][kt], bfk, sacc[1][jt], 0, 0, 0);
        }
      }

      if (diag) {
#pragma unroll
        for (int i = 0; i < 2; ++i)
#pragma unroll
          for (int jt = 0; jt < 4; ++jt) {
            const int kg = k0 + jt * 16 + lrow;
#pragma unroll
            for (int r = 0; r < 4; ++r)
              if (kg > qw + i * 16 + quad * 4 + r) sacc[i][jt][r] = -1e30f;
          }
      }

#pragma unroll
      for (int i = 0; i < 2; ++i)
#pragma unroll
        for (int jt = 0; jt < 4; ++jt)
#pragma unroll
          for (int r = 0; r < 4; ++r) {
            const float p = exp2f(sacc[i][jt][r] - kOff);
            sacc[i][jt][r] = p;
            lst[i][r] += p;
          }

#pragma unroll
      for (int i = 0; i < 2; ++i)
#pragma unroll
        for (int jt = 0; jt < 4; ++jt)
#pragma unroll
          for (int r = 0; r < 4; ++r)
            Ps[(wave * 32 + i * 16 + quad * 4 + r) * 72 + jt * 16 + lrow] =
                (_Float16)sacc[i][jt][r];

      const int ktmax = (k0 >= qw) ? 1 : 2;
      for (int kt = 0; kt < ktmax; ++kt) {
        half8 pf[2];
#pragma unroll
        for (int i = 0; i < 2; ++i)
          pf[i] = *reinterpret_cast<const half8*>(
              &Ps[(wave * 32 + i * 16 + lrow) * 72 + (kt * 4 + quad) * 8]);
#pragma unroll
        for (int jt = 0; jt < 4; ++jt) {
          const int rb = jt * 16 + lrow;
          half8 vf = *reinterpret_cast<const half8*>(
              &Vs[rb * 64 + (((kt * 4 + quad) ^ (rb & 7)) << 3)]);
          oacc[0][jt] = __builtin_amdgcn_mfma_f32_16x16x32_f16(pf[0], vf, oacc[0][jt], 0, 0, 0);
          oacc[1][jt] = __builtin_amdgcn_mfma_f32_16x16x32_f16(pf[1], vf, oacc[1][jt], 0, 0, 0);
        }
      }
    }

    // epilogue: reduce l over 16 cols, accumulate partials
#pragma unroll
    for (int i = 0; i < 2; ++i)
#pragma unroll
      for (int r = 0; r < 4; ++r)
#pragma unroll
        for (int off = 8; off; off >>= 1) lst[i][r] += __shfl_xor(lst[i][r], off);
#pragma unroll
    for (int i = 0; i < 2; ++i)
#pragma unroll
      for (int r = 0; r < 4; ++r) {
        const int qg = qw + i * 16 + quad * 4 + r;
        if (lrow == 0) atomicAdd(Lacc + qg * kH + h, lst[i][r]);
#pragma unroll
        for (int jt = 0; jt < 4; ++jt)
          atomicAdd(Oacc + ((size_t)qg * kH + h) * kDh + jt * 16 + lrow, oacc[i][jt][r]);
      }
  }
}

// ---------------------------------------------------------------- normalize: ho attn columns = Oacc / Lacc
__global__ __launch_bounds__(256) void norm_kernel(
    const float* __restrict__ Oacc, const float* __restrict__ Lacc,
    _Float16* __restrict__ ho) {
  const int idx = blockIdx.x * 256 + threadIdx.x;
  const int q = idx >> 10, rem = idx & 1023;
  const float l = Lacc[(q << 4) + (rem >> 6)];
  ho[(size_t)q * kKOut + kF + rem] = (_Float16)(Oacc[idx] / l);
}

// ---------------------------------------------------------------- launch
extern "C" void kernel_launch(void* const* d_in, const int* in_sizes, int n_in,
                              void* d_out, int out_size, void* d_ws, size_t ws_size,
                              hipStream_t stream) {
  const float* x        = (const float*)d_in[0];
  const float* ln_scale = (const float*)d_in[2];
  const float* ln_bias  = (const float*)d_in[3];
  const float* w_in     = (const float*)d_in[4];
  const float* b_in     = (const float*)d_in[5];
  const float* wq       = (const float*)d_in[6];
  const float* bq       = (const float*)d_in[7];
  const float* wk       = (const float*)d_in[8];
  const float* bk       = (const float*)d_in[9];
  const float* wv       = (const float*)d_in[10];
  const float* bv       = (const float*)d_in[11];
  const float* qn_scale = (const float*)d_in[12];
  const float* kn_scale = (const float*)d_in[13];
  const float* w_mo     = (const float*)d_in[14];
  const float* b_mo     = (const float*)d_in[15];
  const float* w_ao     = (const float*)d_in[16];
  const float* b_ao     = (const float*)d_in[17];
  float* out = (float*)d_out;

  char* ws = (char*)d_ws;
  size_t off = 0;
  auto alloc = [&](size_t bytes) { char* p = ws + off; off += bytes; return p; };
  // alias zone: xn+Wqkv dead after gemm_qkvin; Oacc/Lacc overlay
  char* zone = (char*)alloc((size_t)kS * kD * 2 + (size_t)kNQKV * kD * 2);
  _Float16* xn   = (_Float16*)zone;
  _Float16* Wqkv = (_Float16*)(zone + (size_t)kS * kD * 2);
  float* Oacc = (float*)zone;
  float* Lacc = (float*)(zone + (size_t)kS * kD * 4);
  _Float16* Wout = (_Float16*)alloc((size_t)kD * kKOut * 2);
  float*    bcat = (float*)alloc((size_t)kNQKV * 4);
  float*    bsum = (float*)alloc((size_t)kD * 4);
  _Float16* ho   = (_Float16*)alloc((size_t)kS * kKOut * 2);
  _Float16* q_h  = (_Float16*)alloc((size_t)kS * kD * 2);
  _Float16* k_h  = (_Float16*)alloc((size_t)kS * kD * 2);
  _Float16* v_h  = (_Float16*)alloc((size_t)kS * kD * 2);
  _Float16* v_t  = (_Float16*)alloc((size_t)kS * kD * 2);

  wtrans_all<<<12288, 256, 0, stream>>>(w_in, wq, wk, wv, w_mo, w_ao, Wqkv, Wout);
  biasprep_kernel<<<(kNQKV + kD + 255) / 256, 256, 0, stream>>>(
      b_in, bq, bk, bv, b_mo, b_ao, bcat, bsum);
  ln_kernel<<<kS, 256, 0, stream>>>(x, ln_scale, ln_bias, xn);

  gemm_qkvin<<<dim3(kS / 128, kNQKV / 128), 256, 0, stream>>>(
      xn, Wqkv, bcat, qn_scale, kn_scale, ho, q_h, k_h, v_h);

  htrans_kernel<<<dim3(kD / 32, kS / 32), 256, 0, stream>>>(v_h, v_t, kS, kD);

  zeroacc_kernel<<<(kS * kD + kS * kH + 255) / 256, 256, 0, stream>>>(
      Oacc, kS * kD + kS * kH);

  fattn_kernel<<<768, 256, 0, stream>>>(q_h, k_h, v_t, Oacc, Lacc);

  norm_kernel<<<kS * kD / 256, 256, 0, stream>>>(Oacc, Lacc, ho);

  initout_kernel<<<kS * kD / 256, 256, 0, stream>>>(x, bsum, out);
  gemm_out<<<dim3(kS / 128, kD / 128, 2), 256, 0, stream>>>(ho, Wout, out);
}

// Round 7
// 476.555 us; speedup vs baseline: 12.1800x; 1.0367x over previous
//
#include <hip/hip_runtime.h>
#include <hip/hip_fp16.h>

typedef _Float16 half8 __attribute__((ext_vector_type(8)));
typedef float floatx4 __attribute__((ext_vector_type(4)));

constexpr int kS = 4096;
constexpr int kD = 1024;
constexpr int kH = 16;
constexpr int kDh = 64;
constexpr int kF = 4096;
constexpr int kNQKV = kF + 3 * kD;   // 7168
constexpr int kKOut = kF + kD;       // 5120

__device__ __forceinline__ void async_ld16(const void* g, void* l) {
  __builtin_amdgcn_global_load_lds(
      (const __attribute__((address_space(1))) void*)g,
      (__attribute__((address_space(3))) void*)l, 16, 0, 0);
}

// ---------------------------------------------------------------- all weight transposes in one launch
__global__ __launch_bounds__(256) void wtrans_all(
    const float* __restrict__ w_in, const float* __restrict__ wq,
    const float* __restrict__ wk, const float* __restrict__ wv,
    const float* __restrict__ w_mo, const float* __restrict__ w_ao,
    _Float16* __restrict__ Wqkv, _Float16* __restrict__ Wout) {
  __shared__ float t[32][33];
  int id = blockIdx.x;
  const float* src; _Float16* dst; int N, ldk, noff, koff, nt, kt;
  if (id < 4096)       { src = w_in; dst = Wqkv; N = kF; ldk = kD; noff = 0;        koff = 0;  nt = id & 127; kt = id >> 7; }
  else if (id < 5120)  { id -= 4096; src = wq;  dst = Wqkv; N = kD; ldk = kD; noff = kF;       koff = 0;  nt = id & 31; kt = id >> 5; }
  else if (id < 6144)  { id -= 5120; src = wk;  dst = Wqkv; N = kD; ldk = kD; noff = kF + kD;  koff = 0;  nt = id & 31; kt = id >> 5; }
  else if (id < 7168)  { id -= 6144; src = wv;  dst = Wqkv; N = kD; ldk = kD; noff = kF + 2*kD; koff = 0; nt = id & 31; kt = id >> 5; }
  else if (id < 11264) { id -= 7168; src = w_mo; dst = Wout; N = kD; ldk = kKOut; noff = 0;    koff = 0;  nt = id & 31; kt = id >> 5; }
  else                 { id -= 11264; src = w_ao; dst = Wout; N = kD; ldk = kKOut; noff = 0;   koff = kF; nt = id & 31; kt = id >> 5; }
  const int tid = threadIdx.x;
  const int n0 = nt * 32, k0 = kt * 32;
#pragma unroll
  for (int i = 0; i < 4; ++i) {
    const int kl = (tid >> 5) + i * 8, nl = tid & 31;
    t[kl][nl] = src[(size_t)(k0 + kl) * N + n0 + nl];
  }
  __syncthreads();
#pragma unroll
  for (int i = 0; i < 4; ++i) {
    const int nl = (tid >> 5) + i * 8, kl = tid & 31;
    dst[(size_t)(noff + n0 + nl) * ldk + koff + k0 + kl] = (_Float16)t[kl][nl];
  }
}

// fp16 transpose: src [R][C] -> dst [C][R]
__global__ __launch_bounds__(256) void htrans_kernel(
    const _Float16* __restrict__ src, _Float16* __restrict__ dst, int R, int C) {
  __shared__ _Float16 t[32][34];
  const int tid = threadIdx.x;
  const int c0 = blockIdx.x * 32, r0 = blockIdx.y * 32;
#pragma unroll
  for (int i = 0; i < 4; ++i) {
    const int rl = (tid >> 5) + i * 8, cl = tid & 31;
    t[rl][cl] = src[(size_t)(r0 + rl) * C + c0 + cl];
  }
  __syncthreads();
#pragma unroll
  for (int i = 0; i < 4; ++i) {
    const int cl = (tid >> 5) + i * 8, rl = tid & 31;
    dst[(size_t)(c0 + cl) * R + r0 + rl] = t[rl][cl];
  }
}

// ---------------------------------------------------------------- bias prep
__global__ __launch_bounds__(256) void biasprep_kernel(
    const float* b_in, const float* bq, const float* bk, const float* bv,
    const float* b_mo, const float* b_ao, float* bcat, float* bsum) {
  const int i = blockIdx.x * 256 + threadIdx.x;
  if (i < kF) bcat[i] = b_in[i];
  else if (i < kF + kD) bcat[i] = bq[i - kF];
  else if (i < kF + 2 * kD) bcat[i] = bk[i - kF - kD];
  else if (i < kNQKV) bcat[i] = bv[i - kF - 2 * kD];
  else if (i < kNQKV + kD) bsum[i - kNQKV] = b_mo[i - kNQKV] + b_ao[i - kNQKV];
}

// ---------------------------------------------------------------- LayerNorm (D=1024) -> fp16
__global__ __launch_bounds__(256) void ln_kernel(
    const float* __restrict__ x, const float* __restrict__ scale,
    const float* __restrict__ bias, _Float16* __restrict__ xn) {
  const int row = blockIdx.x;
  const int tid = threadIdx.x;
  const float* xr = x + (size_t)row * kD;
  float v[4];
  float s = 0.f, sq = 0.f;
#pragma unroll
  for (int i = 0; i < 4; ++i) {
    v[i] = xr[tid + 256 * i];
    s += v[i];
    sq += v[i] * v[i];
  }
  for (int off = 32; off; off >>= 1) {
    s += __shfl_xor(s, off);
    sq += __shfl_xor(sq, off);
  }
  __shared__ float red[8];
  const int wv = tid >> 6;
  if ((tid & 63) == 0) { red[wv] = s; red[wv + 4] = sq; }
  __syncthreads();
  s = red[0] + red[1] + red[2] + red[3];
  sq = red[4] + red[5] + red[6] + red[7];
  const float mean = s * (1.0f / kD);
  const float var = sq * (1.0f / kD) - mean * mean;
  const float rstd = rsqrtf(var + 1e-6f);
#pragma unroll
  for (int i = 0; i < 4; ++i) {
    int d = tid + 256 * i;
    xn[(size_t)row * kD + d] = (_Float16)((v[i] - mean) * rstd * scale[d] + bias[d]);
  }
}

// fast tanh-gelu
__device__ __forceinline__ float fast_gelu(float xv) {
  const float z = 0.7978845608028654f * (xv + 0.044715f * xv * xv * xv);
  const float u = exp2f(fminf(2.885390081777927f * z, 80.0f));
  return xv * u / (1.0f + u);
}

// ---------------------------------------------------------------- fused QKV+MLP-in GEMM (+fused qk-LayerNorm)
__global__ __launch_bounds__(256) void gemm_qkvin(
    const _Float16* __restrict__ A, const _Float16* __restrict__ Bp,
    const float* __restrict__ bcat, const float* __restrict__ qn_scale,
    const float* __restrict__ kn_scale, _Float16* __restrict__ ho,
    _Float16* __restrict__ q, _Float16* __restrict__ k, _Float16* __restrict__ v) {
  __shared__ alignas(16) _Float16 Ts[16 * 512];
  _Float16* As = Ts;
  _Float16* Bs = Ts + 8 * 512;

  const int tid = threadIdx.x;
  const int lane = tid & 63;
  const int wave = tid >> 6;
  const int wm = (wave >> 1) * 64;
  const int wn = (wave & 1) * 64;
  const int m0 = blockIdx.x * 128;
  const int n0 = blockIdx.y * 128;
  const int lrow = lane & 15;
  const int quad = lane >> 4;

  floatx4 acc[4][4] = {};

  for (int k0 = 0; k0 < kD; k0 += 32) {
    __syncthreads();
#pragma unroll
    for (int i = 0; i < 4; ++i) {
      const int chunk = wave * 4 + i;
      const int r = ((chunk & 7) << 4) + (lane >> 2);
      const int csrc = ((lane & 3) ^ ((r >> 1) & 3)) << 3;
      const _Float16* src = (chunk < 8)
          ? A + (size_t)(m0 + r) * kD + k0 + csrc
          : Bp + (size_t)(n0 + r) * kD + k0 + csrc;
      async_ld16(src, Ts + chunk * 512);
    }
    __syncthreads();

    half8 af[4], bf[4];
#pragma unroll
    for (int i = 0; i < 4; ++i) {
      const int ra = wm + i * 16 + lrow;
      const int rb = wn + i * 16 + lrow;
      af[i] = *reinterpret_cast<const half8*>(&As[ra * 32 + ((quad ^ ((ra >> 1) & 3)) << 3)]);
      bf[i] = *reinterpret_cast<const half8*>(&Bs[rb * 32 + ((quad ^ ((rb >> 1) & 3)) << 3)]);
    }
#pragma unroll
    for (int i = 0; i < 4; ++i)
#pragma unroll
      for (int j = 0; j < 4; ++j)
        acc[i][j] = __builtin_amdgcn_mfma_f32_16x16x32_f16(af[i], bf[j], acc[i][j], 0, 0, 0);
  }

  const int nblk = n0 + wn;
  if (nblk < kF) {
#pragma unroll
    for (int i = 0; i < 4; ++i) {
      const int gm = m0 + wm + i * 16 + quad * 4;
#pragma unroll
      for (int j = 0; j < 4; ++j) {
        const int gn = nblk + j * 16 + lrow;
        const float bn = bcat[gn];
#pragma unroll
        for (int r = 0; r < 4; ++r)
          ho[(size_t)(gm + r) * kKOut + gn] = (_Float16)fast_gelu(acc[i][j][r] + bn);
      }
    }
  } else if (nblk >= kF + 2 * kD) {
#pragma unroll
    for (int i = 0; i < 4; ++i) {
      const int gm = m0 + wm + i * 16 + quad * 4;
#pragma unroll
      for (int j = 0; j < 4; ++j) {
        const int gn = nblk + j * 16 + lrow;
        const float bn = bcat[gn];
#pragma unroll
        for (int r = 0; r < 4; ++r)
          v[(size_t)(gm + r) * kD + ((gn - kF) & (kD - 1))] = (_Float16)(acc[i][j][r] + bn);
      }
    }
  } else {
    const bool isq = nblk < kF + kD;
    const float* nsc = isq ? qn_scale : kn_scale;
    const float sm = isq ? 0.18033688f : 1.0f;  // q: fold 0.125*log2e
    _Float16* dst = isq ? q : k;
    const int col0 = (nblk - kF) & (kD - 1);
    float bj[4];
#pragma unroll
    for (int j = 0; j < 4; ++j) bj[j] = bcat[nblk + j * 16 + lrow];
#pragma unroll
    for (int i = 0; i < 4; ++i) {
      const int gm = m0 + wm + i * 16 + quad * 4;
#pragma unroll
      for (int r = 0; r < 4; ++r) {
        float vals[4], s1 = 0.f, s2 = 0.f;
#pragma unroll
        for (int j = 0; j < 4; ++j) {
          const float vv = acc[i][j][r] + bj[j];
          vals[j] = vv; s1 += vv; s2 += vv * vv;
        }
#pragma unroll
        for (int off = 1; off <= 8; off <<= 1) {
          s1 += __shfl_xor(s1, off);
          s2 += __shfl_xor(s2, off);
        }
        const float mean = s1 * (1.0f / 64.0f);
        const float rstd = rsqrtf(s2 * (1.0f / 64.0f) - mean * mean + 1e-6f);
#pragma unroll
        for (int j = 0; j < 4; ++j) {
          const int d = j * 16 + lrow;
          dst[(size_t)(gm + r) * kD + col0 + d] =
              (_Float16)((vals[j] - mean) * rstd * nsc[d] * sm);
        }
      }
    }
  }
}

// ---------------------------------------------------------------- prep: out = x + bsum ; zero Oacc/Lacc
__global__ __launch_bounds__(256) void prep_kernel(
    const float* __restrict__ x, const float* __restrict__ bsum,
    float* __restrict__ out, float* __restrict__ Oacc, float* __restrict__ Lacc) {
  const int i = blockIdx.x * 256 + threadIdx.x;
  if (i < kS * kD) {
    out[i] = x[i] + bsum[i & (kD - 1)];
    Oacc[i] = 0.f;
  } else if (i < kS * kD + kS * kH) {
    Lacc[i - kS * kD] = 0.f;
  }
}

// ---------------------------------------------------------------- fused out GEMM, 128x128, split-K=2, atomic accumulate
__global__ __launch_bounds__(256) void gemm_out(
    const _Float16* __restrict__ A, const _Float16* __restrict__ Bp,
    float* __restrict__ out) {
  __shared__ alignas(16) _Float16 Ts[16 * 512];
  _Float16* As = Ts;
  _Float16* Bs = Ts + 8 * 512;

  const int tid = threadIdx.x;
  const int lane = tid & 63;
  const int wave = tid >> 6;
  const int wm = (wave >> 1) * 64;
  const int wn = (wave & 1) * 64;
  const int m0 = blockIdx.x * 128;
  const int n0 = blockIdx.y * 128;
  const int kbeg = blockIdx.z * (kKOut / 2);
  const int lrow = lane & 15;
  const int quad = lane >> 4;

  floatx4 acc[4][4] = {};

  for (int k0 = kbeg; k0 < kbeg + kKOut / 2; k0 += 32) {
    __syncthreads();
#pragma unroll
    for (int i = 0; i < 4; ++i) {
      const int chunk = wave * 4 + i;
      const int r = ((chunk & 7) << 4) + (lane >> 2);
      const int csrc = ((lane & 3) ^ ((r >> 1) & 3)) << 3;
      const _Float16* src = (chunk < 8)
          ? A + (size_t)(m0 + r) * kKOut + k0 + csrc
          : Bp + (size_t)(n0 + r) * kKOut + k0 + csrc;
      async_ld16(src, Ts + chunk * 512);
    }
    __syncthreads();

    half8 af[4], bf[4];
#pragma unroll
    for (int i = 0; i < 4; ++i) {
      const int ra = wm + i * 16 + lrow;
      const int rb = wn + i * 16 + lrow;
      af[i] = *reinterpret_cast<const half8*>(&As[ra * 32 + ((quad ^ ((ra >> 1) & 3)) << 3)]);
      bf[i] = *reinterpret_cast<const half8*>(&Bs[rb * 32 + ((quad ^ ((rb >> 1) & 3)) << 3)]);
    }
#pragma unroll
    for (int i = 0; i < 4; ++i)
#pragma unroll
      for (int j = 0; j < 4; ++j)
        acc[i][j] = __builtin_amdgcn_mfma_f32_16x16x32_f16(af[i], bf[j], acc[i][j], 0, 0, 0);
  }

#pragma unroll
  for (int i = 0; i < 4; ++i) {
    const int gm = m0 + wm + i * 16 + quad * 4;
#pragma unroll
    for (int j = 0; j < 4; ++j) {
      const int gn = n0 + wn + j * 16 + lrow;
#pragma unroll
      for (int r = 0; r < 4; ++r)
        atomicAdd(out + (size_t)(gm + r) * kD + gn, acc[i][j][r]);
    }
  }
}

// ---------------------------------------------------------------- flash attention v5: 64-row tiles + XCD swizzle
// grid 1024 (1D): xcd=id&7, heads {2x,2x+1} pinned per XCD (K/V 2MB <= 4MB L2).
// 64 q-rows/block (16/wave), balanced pairs {p,63-p}, 2 k-splits.
// No-max softmax (|s|<=8 after qk-LN; 0.125*log2e folded into q), per-lane l,
// additive cross-split combination via atomicAdd.
__global__ __launch_bounds__(256) void fattn_kernel(
    const _Float16* __restrict__ Q, const _Float16* __restrict__ K,
    const _Float16* __restrict__ Vt, float* __restrict__ Oacc,
    float* __restrict__ Lacc) {
  __shared__ alignas(16) _Float16 Qs[64 * 64];   // 8 KB swizzled (c ^ (r&7))
  __shared__ alignas(16) _Float16 Ks[64 * 64];   // 8 KB rows=key
  __shared__ alignas(16) _Float16 Vs[64 * 64];   // 8 KB rows=dh
  __shared__ alignas(16) _Float16 Ps[64 * 72];   // 9 KB padded

  const int tid = threadIdx.x;
  const int lane = tid & 63;
  const int wave = tid >> 6;
  const int lrow = lane & 15;
  const int quad = lane >> 4;

  const int id = blockIdx.x;
  const int xcd = id & 7;
  const int idx = id >> 3;            // 0..127 per XCD
  const int h = (xcd << 1) | (idx & 1);
  const int rem = idx >> 1;           // 0..63
  const int pair = rem & 31;          // 32 pairs of 64-row q-tiles
  const int split = rem >> 5;         // 0..1

  const int rs = lane >> 3;
  const int cs = lane & 7;
  constexpr float kOff = 11.5415603f;  // 8*log2(e)

  for (int pass = 0; pass < 2; ++pass) {
    const int qtile = pass ? (63 - pair) : pair;
    const int qbase = qtile * 64;

    __syncthreads();
#pragma unroll
    for (int i = 0; i < 2; ++i) {  // Q: 8 chunks x 8 rows
      const int chunk = wave * 2 + i;
      const int r = chunk * 8 + rs;
      async_ld16(Q + (size_t)(qbase + r) * kD + h * kDh + ((cs ^ (r & 7)) << 3),
                 Qs + chunk * 512);
    }
    __syncthreads();

    half8 qf[2];
#pragma unroll
    for (int kt = 0; kt < 2; ++kt) {
      const int row = wave * 16 + lrow;
      qf[kt] = *reinterpret_cast<const half8*>(
          &Qs[row * 64 + (((kt * 4 + quad) ^ (row & 7)) << 3)]);
    }

    float lst[4] = {0.f, 0.f, 0.f, 0.f};
    floatx4 oacc[4] = {};
    const int qw = qbase + wave * 16;

    for (int t = split; t <= qtile; t += 2) {
      const int k0 = t * 64;
      __syncthreads();
#pragma unroll
      for (int i = 0; i < 4; ++i) {
        const int c2 = wave * 4 + i;
        if (c2 < 8) {
          const int r = c2 * 8 + rs;
          async_ld16(K + (size_t)(k0 + r) * kD + h * kDh + ((cs ^ (r & 7)) << 3),
                     Ks + c2 * 512);
        } else {
          const int c = c2 - 8;
          const int r = c * 8 + rs;
          async_ld16(Vt + (size_t)(h * kDh + r) * kS + k0 + ((cs ^ (r & 7)) << 3),
                     Vs + c * 512);
        }
      }
      __syncthreads();

      const bool diag = (t == qtile);

      floatx4 sacc[4] = {};
#pragma unroll
      for (int jt = 0; jt < 4; ++jt) {
        if (diag && jt > wave) continue;  // fully-masked key block
#pragma unroll
        for (int kt = 0; kt < 2; ++kt) {
          const int rb = jt * 16 + lrow;
          half8 bfk = *reinterpret_cast<const half8*>(
              &Ks[rb * 64 + (((kt * 4 + quad) ^ (rb & 7)) << 3)]);
          sacc[jt] = __builtin_amdgcn_mfma_f32_16x16x32_f16(qf[kt], bfk, sacc[jt], 0, 0, 0);
        }
      }

      if (diag) {
#pragma unroll
        for (int jt = 0; jt < 4; ++jt) {
          const int kg = k0 + jt * 16 + lrow;
#pragma unroll
          for (int r = 0; r < 4; ++r)
            if (kg > qw + quad * 4 + r) sacc[jt][r] = -1e30f;
        }
      }

#pragma unroll
      for (int jt = 0; jt < 4; ++jt)
#pragma unroll
        for (int r = 0; r < 4; ++r) {
          const float p = exp2f(sacc[jt][r] - kOff);
          sacc[jt][r] = p;
          lst[r] += p;
        }

#pragma unroll
      for (int jt = 0; jt < 4; ++jt)
#pragma unroll
        for (int r = 0; r < 4; ++r)
          Ps[(wave * 16 + quad * 4 + r) * 72 + jt * 16 + lrow] = (_Float16)sacc[jt][r];

      const int ktmax = (diag && wave < 2) ? 1 : 2;
      for (int kt = 0; kt < ktmax; ++kt) {
        half8 pf = *reinterpret_cast<const half8*>(
            &Ps[(wave * 16 + lrow) * 72 + (kt * 4 + quad) * 8]);
#pragma unroll
        for (int jt = 0; jt < 4; ++jt) {
          const int rb = jt * 16 + lrow;
          half8 vf = *reinterpret_cast<const half8*>(
              &Vs[rb * 64 + (((kt * 4 + quad) ^ (rb & 7)) << 3)]);
          oacc[jt] = __builtin_amdgcn_mfma_f32_16x16x32_f16(pf, vf, oacc[jt], 0, 0, 0);
        }
      }
    }

    // epilogue: reduce l over 16 cols, accumulate partials
#pragma unroll
    for (int r = 0; r < 4; ++r)
#pragma unroll
      for (int off = 8; off; off >>= 1) lst[r] += __shfl_xor(lst[r], off);
#pragma unroll
    for (int r = 0; r < 4; ++r) {
      const int qg = qw + quad * 4 + r;
      if (lrow == 0) atomicAdd(Lacc + qg * kH + h, lst[r]);
#pragma unroll
      for (int jt = 0; jt < 4; ++jt)
        atomicAdd(Oacc + ((size_t)qg * kH + h) * kDh + jt * 16 + lrow, oacc[jt][r]);
    }
  }
}

// ---------------------------------------------------------------- normalize: ho attn columns = Oacc / Lacc
__global__ __launch_bounds__(256) void norm_kernel(
    const float* __restrict__ Oacc, const float* __restrict__ Lacc,
    _Float16* __restrict__ ho) {
  const int idx = blockIdx.x * 256 + threadIdx.x;
  const int q = idx >> 10, rem = idx & 1023;
  const float l = Lacc[(q << 4) + (rem >> 6)];
  ho[(size_t)q * kKOut + kF + rem] = (_Float16)(Oacc[idx] / l);
}

// ---------------------------------------------------------------- launch
extern "C" void kernel_launch(void* const* d_in, const int* in_sizes, int n_in,
                              void* d_out, int out_size, void* d_ws, size_t ws_size,
                              hipStream_t stream) {
  const float* x        = (const float*)d_in[0];
  const float* ln_scale = (const float*)d_in[2];
  const float* ln_bias  = (const float*)d_in[3];
  const float* w_in     = (const float*)d_in[4];
  const float* b_in     = (const float*)d_in[5];
  const float* wq       = (const float*)d_in[6];
  const float* bq       = (const float*)d_in[7];
  const float* wk       = (const float*)d_in[8];
  const float* bk       = (const float*)d_in[9];
  const float* wv       = (const float*)d_in[10];
  const float* bv       = (const float*)d_in[11];
  const float* qn_scale = (const float*)d_in[12];
  const float* kn_scale = (const float*)d_in[13];
  const float* w_mo     = (const float*)d_in[14];
  const float* b_mo     = (const float*)d_in[15];
  const float* w_ao     = (const float*)d_in[16];
  const float* b_ao     = (const float*)d_in[17];
  float* out = (float*)d_out;

  char* ws = (char*)d_ws;
  size_t off = 0;
  auto alloc = [&](size_t bytes) { char* p = ws + off; off += bytes; return p; };
  // alias zone: xn+Wqkv dead after gemm_qkvin; Oacc/Lacc overlay
  char* zone = (char*)alloc((size_t)kS * kD * 2 + (size_t)kNQKV * kD * 2);
  _Float16* xn   = (_Float16*)zone;
  _Float16* Wqkv = (_Float16*)(zone + (size_t)kS * kD * 2);
  float* Oacc = (float*)zone;
  float* Lacc = (float*)(zone + (size_t)kS * kD * 4);
  _Float16* Wout = (_Float16*)alloc((size_t)kD * kKOut * 2);
  float*    bcat = (float*)alloc((size_t)kNQKV * 4);
  float*    bsum = (float*)alloc((size_t)kD * 4);
  _Float16* ho   = (_Float16*)alloc((size_t)kS * kKOut * 2);
  _Float16* q_h  = (_Float16*)alloc((size_t)kS * kD * 2);
  _Float16* k_h  = (_Float16*)alloc((size_t)kS * kD * 2);
  _Float16* v_h  = (_Float16*)alloc((size_t)kS * kD * 2);
  _Float16* v_t  = (_Float16*)alloc((size_t)kS * kD * 2);

  wtrans_all<<<12288, 256, 0, stream>>>(w_in, wq, wk, wv, w_mo, w_ao, Wqkv, Wout);
  biasprep_kernel<<<(kNQKV + kD + 255) / 256, 256, 0, stream>>>(
      b_in, bq, bk, bv, b_mo, b_ao, bcat, bsum);
  ln_kernel<<<kS, 256, 0, stream>>>(x, ln_scale, ln_bias, xn);

  gemm_qkvin<<<dim3(kS / 128, kNQKV / 128), 256, 0, stream>>>(
      xn, Wqkv, bcat, qn_scale, kn_scale, ho, q_h, k_h, v_h);

  htrans_kernel<<<dim3(kD / 32, kS / 32), 256, 0, stream>>>(v_h, v_t, kS, kD);

  prep_kernel<<<(kS * kD + kS * kH + 255) / 256, 256, 0, stream>>>(
      x, bsum, out, Oacc, Lacc);

  fattn_kernel<<<1024, 256, 0, stream>>>(q_h, k_h, v_t, Oacc, Lacc);

  norm_kernel<<<kS * kD / 256, 256, 0, stream>>>(Oacc, Lacc, ho);

  gemm_out<<<dim3(kS / 128, kD / 128, 2), 256, 0, stream>>>(ho, Wout, out);
}